// Round 1
// baseline (219.709 us; speedup 1.0000x reference)
//
#include <hip/hip_runtime.h>
#include <math.h>

#define N_SB 2
#define N_V  3
#define N_R  2048
#define N_C  1000
#define N_S  40
#define N_G  15
#define N_HID 256
#define NCPAD 1024
#define HW 65536

__device__ __forceinline__ int swz(int i) { return i ^ ((i >> 5) & 31); }

__device__ __forceinline__ float wave_sum(float v) {
#pragma unroll
  for (int off = 32; off > 0; off >>= 1) v += __shfl_xor(v, off);
  return v;
}

// XLA/Eigen f32 erf: rational poly in x^2, clamp to +-erfinv(1-2^-23).
__device__ __forceinline__ float erf_xla(float x) {
  const float c = 3.832506856900711f;
  x = fminf(fmaxf(x, -c), c);
  float x2 = __fmul_rn(x, x);
  float p = 0.00022905065861350646f;
  p = __fadd_rn(__fmul_rn(p, x2), 0.0034082910107109506f);
  p = __fadd_rn(__fmul_rn(p, x2), 0.050955695062380861f);
  p = __fadd_rn(__fmul_rn(p, x2), 0.18520832239976145f);
  p = __fadd_rn(__fmul_rn(p, x2), 1.128379143519084f);
  float q = -1.1791602954361697e-7f;
  q = __fadd_rn(__fmul_rn(q, x2), 0.000023547966471313185f);
  q = __fadd_rn(__fmul_rn(q, x2), 0.0010179625278914885f);
  q = __fadd_rn(__fmul_rn(q, x2), 0.014070470171167667f);
  q = __fadd_rn(__fmul_rn(q, x2), 0.11098505178285362f);
  q = __fadd_rn(__fmul_rn(q, x2), 0.49746925110067538f);
  q = __fadd_rn(__fmul_rn(q, x2), 1.0f);
  return __fdiv_rn(__fmul_rn(x, p), q);
}

__device__ __forceinline__ float bitonic64(float v, int lane) {
#pragma unroll
  for (int k = 2; k <= 64; k <<= 1) {
#pragma unroll
    for (int j = k >> 1; j >= 1; j >>= 1) {
      float o = __shfl_xor(v, j);
      bool up = ((lane & k) == 0);
      bool lower = ((lane & j) == 0);
      v = (lower == up) ? fminf(v, o) : fmaxf(v, o);
    }
  }
  return v;
}

__global__ __launch_bounds__(256, 2)
void nerf_all(const float* __restrict__ rays, const float* __restrict__ poses,
              const float* __restrict__ focal, const float* __restrict__ cvec,
              const float* __restrict__ dmap, const float* __restrict__ smap,
              const float* __restrict__ nmap, const float* __restrict__ W1,
              const float* __restrict__ b1, const float* __restrict__ W2,
              const float* __restrict__ b2, const float* __restrict__ uc,
              const float* __restrict__ gn, const float* __restrict__ uf,
              float* __restrict__ out)
{
  __shared__ float s_pt[4][NCPAD];
  __shared__ float s_zc[4][NCPAD];
  __shared__ float s_w1[6 * N_HID];
  __shared__ float s_b1v[N_HID];
  __shared__ float s_w2[N_HID * 4];
  __shared__ float s_b2v[4];

  const int tid = threadIdx.x;
  const int wid = tid >> 6;
  const int lane = tid & 63;
  const int ray = blockIdx.x * 4 + wid;   // 0..4095 = sb*N_R + r
  const int sb = ray >> 11;

  // stage MLP weights (used after the post-phase-A barrier)
  for (int i = tid; i < 6 * N_HID; i += 256) s_w1[i] = W1[i];
  for (int i = tid; i < N_HID; i += 256) s_b1v[i] = b1[i];
  for (int i = tid; i < N_HID * 4; i += 256) s_w2[i] = W2[i];
  if (tid < 4) s_b2v[tid] = b2[tid];

  const float* rp = rays + (size_t)ray * 8;
  const float ox = rp[0], oy = rp[1], oz = rp[2];
  const float dx = rp[3], dy = rp[4], dz = rp[5];
  const float nearv = rp[6], farv = rp[7];

  const float lindelta = 0.999f / 999.0f;                     // jnp.linspace delta
  const float ssv = __fdiv_rn(__fsub_rn(farv, nearv), 1000.0f);
  const float sshalf = __fmul_rn(ssv, 0.5f);
  const float SQRT2 = 1.41421356237309515f;

  float* ptl = s_pt[wid];
  float* zcl = s_zc[wid];

  // ---------------- Phase A: pt[i] = max over views ----------------
#pragma unroll 1
  for (int v = 0; v < N_V; ++v) {
    const float* pp = poses + (size_t)(sb * N_V + v) * 16;
    const float R00 = pp[0], R01 = pp[1], R02 = pp[2], t0 = pp[3];
    const float R10 = pp[4], R11 = pp[5], R12 = pp[6], t1 = pp[7];
    const float R20 = pp[8], R21 = pp[9], R22 = pp[10], t2 = pp[11];
    const float fx = focal[(sb * N_V + v) * 2 + 0];
    const float fy = focal[(sb * N_V + v) * 2 + 1];
    const float cx = cvec[(sb * N_V + v) * 2 + 0];
    const float cy = cvec[(sb * N_V + v) * 2 + 1];
    const float rdx = __fadd_rn(__fadd_rn(__fmul_rn(R00, dx), __fmul_rn(R01, dy)), __fmul_rn(R02, dz));
    const float rdy = __fadd_rn(__fadd_rn(__fmul_rn(R10, dx), __fmul_rn(R11, dy)), __fmul_rn(R12, dz));
    const float rdz = __fadd_rn(__fadd_rn(__fmul_rn(R20, dx), __fmul_rn(R21, dy)), __fmul_rn(R22, dz));
    const float* dmv = dmap + (size_t)(sb * N_V + v) * HW;
    const float* smv = smap + (size_t)(sb * N_V + v) * HW;
    const float* nmv = nmap + (size_t)(sb * N_V + v) * 3 * HW;

#pragma unroll 1
    for (int it = 0; it < 16; ++it) {
      const int i = it * 64 + lane;
      if (i >= N_C) continue;
      const int si = swz(i);
      float zc;
      if (v == 0) {
        float u = uc[(size_t)ray * N_C + i];
        float zs = __fadd_rn(__fmul_rn((float)i, lindelta), __fmul_rn(u, 0.001f));
        zc = __fadd_rn(__fmul_rn(nearv, __fsub_rn(1.0f, zs)), __fmul_rn(farv, zs));
        zcl[si] = zc;
      } else {
        zc = zcl[si];   // same lane, same address as the v==0 write: in-order
      }
      const float xw = __fadd_rn(ox, __fmul_rn(zc, dx));
      const float yw = __fadd_rn(oy, __fmul_rn(zc, dy));
      const float zw = __fadd_rn(oz, __fmul_rn(zc, dz));
      const float Xc = __fadd_rn(__fadd_rn(__fadd_rn(__fmul_rn(R00, xw), __fmul_rn(R01, yw)), __fmul_rn(R02, zw)), t0);
      const float Yc = __fadd_rn(__fadd_rn(__fadd_rn(__fmul_rn(R10, xw), __fmul_rn(R11, yw)), __fmul_rn(R12, zw)), t1);
      const float Zc = __fadd_rn(__fadd_rn(__fadd_rn(__fmul_rn(R20, xw), __fmul_rn(R21, yw)), __fmul_rn(R22, zw)), t2);
      const float iu = __fdiv_rn(Xc, Zc);
      const float iv = __fdiv_rn(Yc, Zc);
      const float su = __fadd_rn(__fmul_rn(iu, fx), cx);
      const float sv = __fadd_rn(__fmul_rn(iv, fy), cy);
      const float unorm = __fsub_rn(__fmul_rn(__fmul_rn(su, 1.0f / 256.0f), 2.0f), 1.0f);
      const float vnorm = __fsub_rn(__fmul_rn(__fmul_rn(sv, 1.0f / 256.0f), 2.0f), 1.0f);
      const float xf = __fsub_rn(__fmul_rn(__fmul_rn(__fadd_rn(unorm, 1.0f), 0.5f), 256.0f), 0.5f);
      const float yf = __fsub_rn(__fmul_rn(__fmul_rn(__fadd_rn(vnorm, 1.0f), 0.5f), 256.0f), 0.5f);
      const int px = (int)fminf(fmaxf(rintf(xf), 0.0f), 255.0f);
      const int py = (int)fminf(fmaxf(rintf(yf), 0.0f), 255.0f);
      const int lin = py * 256 + px;
      const float rd = dmv[lin];
      const float rs = smv[lin];
      const float n0 = nmv[lin];
      const float n1 = nmv[HW + lin];
      const float n2 = nmv[2 * HW + lin];
      const float cosd = __fadd_rn(__fadd_rn(__fmul_rn(rdx, n0), __fmul_rn(rdy, n1)), __fmul_rn(rdz, n2));
      const bool m = (rs != 0.0f) && (fabsf(__fsub_rn(rd, Zc)) < 0.05f) && (cosd <= 0.0f);
      const float invv = __fdiv_rn(1.0f, __fmul_rn(m ? rs : 1.0f, SQRT2));
      const float a1 = __fmul_rn(__fsub_rn(__fadd_rn(Zc, sshalf), rd), invv);
      const float a2 = __fmul_rn(__fsub_rn(__fsub_rn(Zc, sshalf), rd), invv);
      const float lik = __fmul_rn(0.5f, fabsf(__fsub_rn(erf_xla(a1), erf_xla(a2))));
      const float ptv = m ? lik : 0.0f;
      if (v == 0) ptl[si] = ptv;
      else ptl[si] = fmaxf(ptl[si], ptv);   // max over views is order-exact
    }
  }

  __syncthreads();   // orders phase-A LDS writes vs cross-lane reads below

  // ---------------- Phase B: opaque scan + moments ----------------
  const int c0 = lane * 16;
  int c1 = c0 + 16; if (c1 > N_C) c1 = N_C;   // lane 63 empty

  float lp = 1.0f;
  for (int i = c0; i < c1; ++i) lp *= (1.0f - ptl[swz(i)]);
  float inc = lp;
#pragma unroll
  for (int off = 1; off < 64; off <<= 1) {
    float o = __shfl_up(inc, off);
    if (lane >= off) inc *= o;
  }
  float exc = __shfl_up(inc, 1);
  if (lane == 0) exc = 1.0f;

  float accO = 0.0f, accZO = 0.0f;
  bool anynz = false;
  {
    float run = exc;
    for (int i = c0; i < c1; ++i) {
      float p = ptl[swz(i)];
      float o = p * run;
      run *= (1.0f - p);
      accO += o;
      accZO += zcl[swz(i)] * o;
      anynz |= (o != 0.0f);
    }
  }
  accO = wave_sum(accO);
  accZO = wave_sum(accZO);
  const bool raymask = (__any(anynz) != 0);
  const float swd = (accO > 0.0f) ? accO : 1.0f;
  const float meanz = __fdiv_rn(accZO, swd);
  float accV = 0.0f;
  {
    float run = exc;
    for (int i = c0; i < c1; ++i) {
      float p = ptl[swz(i)];
      float o = p * run;
      run *= (1.0f - p);
      float d = zcl[swz(i)] - meanz;
      accV += o * d * d;
    }
  }
  accV = wave_sum(accV);
  const float stdz = sqrtf(__fdiv_rn(accV, swd));

  // ---------------- Phase C: stable top-25 ----------------
  float sortv = 0.0f;
#pragma unroll 1
  for (int k = 0; k < N_S - N_G; ++k) {
    float bv = -2.0f; int bi = 0x40000000;
#pragma unroll 1
    for (int it = 0; it < 16; ++it) {
      int i = it * 64 + lane;
      if (i < N_C) {
        float vv = ptl[swz(i)];
        if (vv > bv || (vv == bv && i < bi)) { bv = vv; bi = i; }
      }
    }
#pragma unroll
    for (int off = 1; off < 64; off <<= 1) {
      float ov = __shfl_xor(bv, off);
      int oi = __shfl_xor(bi, off);
      if (ov > bv || (ov == bv && oi < bi)) { bv = ov; bi = oi; }
    }
    float zk = (bv == 0.0f) ? 0.0f : zcl[swz(bi)];
    if (lane == k) sortv = zk;
    if (lane == 0) ptl[swz(bi)] = -1.0f;   // remove winner
    __syncthreads();                        // uniform: all waves do 25 rounds
  }

  // ---------------- Phase D: gaussian slots ----------------
  if (lane >= N_S - N_G && lane < N_S) {
    float g = gn[(size_t)ray * N_G + (lane - (N_S - N_G))];
    sortv = raymask ? (g * stdz + meanz) : 0.0f;
  }
  if (lane >= N_S) sortv = INFINITY;

  // ---------------- Phase E: sort, miss-fill, sort ----------------
  float z = bitonic64(sortv, lane);
  const bool miss = (lane < N_S) && (z == 0.0f);
  const int nmiss_raw = __popcll(__ballot(miss));
  const int nmiss = (nmiss_raw < 1) ? 1 : nmiss_raw;
  const float stepf = __fdiv_rn(__fsub_rn(farv, nearv), (float)nmiss);
  if (miss) {
    float ufv = uf[(size_t)ray * N_S + lane];
    z = __fadd_rn(__fadd_rn(nearv, __fmul_rn((float)lane, stepf)), __fmul_rn(ufv, stepf));
  }
  z = bitonic64(z, lane);

  // ---------------- Phase F: composite ----------------
  const float zn = __shfl_down(z, 1);
  const float delta = (lane == N_S - 1) ? (farv - z) : (zn - z);

  const float pxw = ox + z * dx;
  const float pyw = oy + z * dy;
  const float pzw = oz + z * dz;

  float a0 = 0.0f, a1s = 0.0f, a2s = 0.0f, a3s = 0.0f;
#pragma unroll 4
  for (int j = 0; j < N_HID; ++j) {
    float h = s_b1v[j];
    h = fmaf(pxw, s_w1[j], h);
    h = fmaf(pyw, s_w1[N_HID + j], h);
    h = fmaf(pzw, s_w1[2 * N_HID + j], h);
    h = fmaf(dx, s_w1[3 * N_HID + j], h);
    h = fmaf(dy, s_w1[4 * N_HID + j], h);
    h = fmaf(dz, s_w1[5 * N_HID + j], h);
    h = fmaxf(h, 0.0f);
    a0 = fmaf(h, s_w2[j * 4 + 0], a0);
    a1s = fmaf(h, s_w2[j * 4 + 1], a1s);
    a2s = fmaf(h, s_w2[j * 4 + 2], a2s);
    a3s = fmaf(h, s_w2[j * 4 + 3], a3s);
  }
  const float r0 = a0 + s_b2v[0];
  const float r1 = a1s + s_b2v[1];
  const float r2 = a2s + s_b2v[2];
  const float sig = a3s + s_b2v[3];
  const float rsig = fmaxf(sig, 0.0f);
  const float alpha = 1.0f - expf(-delta * rsig);

  float factor = (lane < N_S) ? ((1.0f - alpha) + 1e-10f) : 1.0f;
  float incp = factor;
#pragma unroll
  for (int off = 1; off < 64; off <<= 1) {
    float o = __shfl_up(incp, off);
    if (lane >= off) incp *= o;
  }
  float T = __shfl_up(incp, 1);
  if (lane == 0) T = 1.0f;

  const float w = (lane < N_S) ? alpha * T : 0.0f;
  const float wz = (lane < N_S) ? w * z : 0.0f;
  const float wr0 = (lane < N_S) ? w * r0 : 0.0f;
  const float wr1 = (lane < N_S) ? w * r1 : 0.0f;
  const float wr2 = (lane < N_S) ? w * r2 : 0.0f;

  const float wsum = wave_sum(w);
  const float dsum = wave_sum(wz);
  const float c0s = wave_sum(wr0);
  const float c1s = wave_sum(wr1);
  const float c2s = wave_sum(wr2);

  if (lane < N_S) out[(size_t)ray * N_S + lane] = w;
  if (lane == 0) {
    float* rgbo = out + (size_t)N_SB * N_R * N_S + (size_t)ray * 3;
    rgbo[0] = (c0s + 1.0f) - wsum;
    rgbo[1] = (c1s + 1.0f) - wsum;
    rgbo[2] = (c2s + 1.0f) - wsum;
    out[(size_t)N_SB * N_R * N_S + (size_t)N_SB * N_R * 3 + ray] = dsum;
  }
}

extern "C" void kernel_launch(void* const* d_in, const int* in_sizes, int n_in,
                              void* d_out, int out_size, void* d_ws, size_t ws_size,
                              hipStream_t stream) {
  const float* rays  = (const float*)d_in[0];
  const float* poses = (const float*)d_in[1];
  const float* focal = (const float*)d_in[2];
  const float* cvec  = (const float*)d_in[3];
  const float* dmap  = (const float*)d_in[4];
  const float* smap  = (const float*)d_in[5];
  const float* nmap  = (const float*)d_in[6];
  const float* W1p   = (const float*)d_in[7];
  const float* b1p   = (const float*)d_in[8];
  const float* W2p   = (const float*)d_in[9];
  const float* b2p   = (const float*)d_in[10];
  const float* ucp   = (const float*)d_in[11];
  const float* gnp   = (const float*)d_in[12];
  const float* ufp   = (const float*)d_in[13];
  float* outp = (float*)d_out;

  dim3 grid((N_SB * N_R) / 4);
  dim3 block(256);
  nerf_all<<<grid, block, 0, stream>>>(rays, poses, focal, cvec, dmap, smap, nmap,
                                       W1p, b1p, W2p, b2p, ucp, gnp, ufp, outp);
}

// Round 2
// 177.111 us; speedup vs baseline: 1.2405x; 1.2405x over previous
//
#include <hip/hip_runtime.h>
#include <math.h>

#define N_SB 2
#define N_V  3
#define N_R  2048
#define N_C  1000
#define N_S  40
#define N_G  15
#define N_HID 256
#define HW 65536
#define KPT 4
#define NACT 250   // 1000 = 250 threads * 4 samples

__device__ __forceinline__ float wave_sum(float v) {
#pragma unroll
  for (int off = 32; off > 0; off >>= 1) v += __shfl_xor(v, off);
  return v;
}

// XLA/Eigen f32 erf: rational poly in x^2, clamp to +-erfinv(1-2^-23).
__device__ __forceinline__ float erf_xla(float x) {
  const float c = 3.832506856900711f;
  x = fminf(fmaxf(x, -c), c);
  float x2 = __fmul_rn(x, x);
  float p = 0.00022905065861350646f;
  p = __fadd_rn(__fmul_rn(p, x2), 0.0034082910107109506f);
  p = __fadd_rn(__fmul_rn(p, x2), 0.050955695062380861f);
  p = __fadd_rn(__fmul_rn(p, x2), 0.18520832239976145f);
  p = __fadd_rn(__fmul_rn(p, x2), 1.128379143519084f);
  float q = -1.1791602954361697e-7f;
  q = __fadd_rn(__fmul_rn(q, x2), 0.000023547966471313185f);
  q = __fadd_rn(__fmul_rn(q, x2), 0.0010179625278914885f);
  q = __fadd_rn(__fmul_rn(q, x2), 0.014070470171167667f);
  q = __fadd_rn(__fmul_rn(q, x2), 0.11098505178285362f);
  q = __fadd_rn(__fmul_rn(q, x2), 0.49746925110067538f);
  q = __fadd_rn(__fmul_rn(q, x2), 1.0f);
  return __fdiv_rn(__fmul_rn(x, p), q);
}

__device__ __forceinline__ float bitonic64(float v, int lane) {
#pragma unroll
  for (int k = 2; k <= 64; k <<= 1) {
#pragma unroll
    for (int j = k >> 1; j >= 1; j >>= 1) {
      float o = __shfl_xor(v, j);
      bool up = ((lane & k) == 0);
      bool lower = ((lane & j) == 0);
      v = (lower == up) ? fminf(v, o) : fmaxf(v, o);
    }
  }
  return v;
}

__global__ __launch_bounds__(256, 4)
void nerf_all(const float* __restrict__ rays, const float* __restrict__ poses,
              const float* __restrict__ focal, const float* __restrict__ cvec,
              const float* __restrict__ dmap, const float* __restrict__ smap,
              const float* __restrict__ nmap, const float* __restrict__ W1,
              const float* __restrict__ b1, const float* __restrict__ W2,
              const float* __restrict__ b2, const float* __restrict__ uc,
              const float* __restrict__ gn, const float* __restrict__ uf,
              float* __restrict__ out)
{
  __shared__ float s_w1[6 * N_HID];
  __shared__ float s_b1v[N_HID];
  __shared__ float s_w2[N_HID * 4];
  __shared__ float s_b2v[4];
  __shared__ float s_wtot[4];
  __shared__ float s_sO[4], s_sZ[4], s_sV[4];
  __shared__ int   s_fl[4];
  __shared__ float s_cval[2][4];
  __shared__ int   s_cidx[2][4];
  __shared__ float s_zsel[32];
  __shared__ float s_zarr[N_S], s_darr[N_S];
  __shared__ float4 s_mlp4[N_S];

  const int tid = threadIdx.x;
  const int wid = tid >> 6;
  const int lane = tid & 63;
  const int ray = blockIdx.x;       // one ray per block, 0..4095
  const int sb = ray >> 11;

  // stage MLP weights (ordered before use by the many intervening barriers)
  for (int i = tid; i < 6 * N_HID; i += 256) s_w1[i] = W1[i];
  for (int i = tid; i < N_HID; i += 256) s_b1v[i] = b1[i];
  for (int i = tid; i < N_HID * 4; i += 256) s_w2[i] = W2[i];
  if (tid < 4) s_b2v[tid] = b2[tid];
  if (tid < 25) s_zsel[tid] = 0.0f;

  const float* rp = rays + (size_t)ray * 8;   // uniform per block -> SGPRs
  const float ox = rp[0], oy = rp[1], oz = rp[2];
  const float dx = rp[3], dy = rp[4], dz = rp[5];
  const float nearv = rp[6], farv = rp[7];

  const float lindelta = 0.999f / 999.0f;
  const float ssv = __fdiv_rn(__fsub_rn(farv, nearv), 1000.0f);
  const float sshalf = __fmul_rn(ssv, 0.5f);
  const float SQRT2 = 1.41421356237309515f;

  const bool act = (tid < NACT);

  // ---------------- Phase A: pt[i] = max over views, registers ----------------
  float zcr[KPT];
  float ptm[KPT] = {0.0f, 0.0f, 0.0f, 0.0f};
  if (act) {
    const float4 u4 = *(const float4*)(uc + (size_t)ray * N_C + (size_t)tid * 4);
    const float uu[4] = {u4.x, u4.y, u4.z, u4.w};
#pragma unroll
    for (int k = 0; k < KPT; ++k) {
      const int i = tid * 4 + k;
      float zs = __fadd_rn(__fmul_rn((float)i, lindelta), __fmul_rn(uu[k], 0.001f));
      zcr[k] = __fadd_rn(__fmul_rn(nearv, __fsub_rn(1.0f, zs)), __fmul_rn(farv, zs));
    }
  } else {
#pragma unroll
    for (int k = 0; k < KPT; ++k) zcr[k] = 0.0f;
  }

#pragma unroll 1
  for (int v = 0; v < N_V; ++v) {
    const float* pp = poses + (size_t)(sb * N_V + v) * 16;
    const float R00 = pp[0], R01 = pp[1], R02 = pp[2], t0 = pp[3];
    const float R10 = pp[4], R11 = pp[5], R12 = pp[6], t1 = pp[7];
    const float R20 = pp[8], R21 = pp[9], R22 = pp[10], t2 = pp[11];
    const float fx = focal[(sb * N_V + v) * 2 + 0];
    const float fy = focal[(sb * N_V + v) * 2 + 1];
    const float cx = cvec[(sb * N_V + v) * 2 + 0];
    const float cy = cvec[(sb * N_V + v) * 2 + 1];
    const float rdx = __fadd_rn(__fadd_rn(__fmul_rn(R00, dx), __fmul_rn(R01, dy)), __fmul_rn(R02, dz));
    const float rdy = __fadd_rn(__fadd_rn(__fmul_rn(R10, dx), __fmul_rn(R11, dy)), __fmul_rn(R12, dz));
    const float rdz = __fadd_rn(__fadd_rn(__fmul_rn(R20, dx), __fmul_rn(R21, dy)), __fmul_rn(R22, dz));
    const float* dmv = dmap + (size_t)(sb * N_V + v) * HW;
    const float* smv = smap + (size_t)(sb * N_V + v) * HW;
    const float* nmv = nmap + (size_t)(sb * N_V + v) * 3 * HW;

    if (act) {
#pragma unroll
      for (int k = 0; k < KPT; ++k) {
        const float zc = zcr[k];
        const float xw = __fadd_rn(ox, __fmul_rn(zc, dx));
        const float yw = __fadd_rn(oy, __fmul_rn(zc, dy));
        const float zw = __fadd_rn(oz, __fmul_rn(zc, dz));
        const float Xc = __fadd_rn(__fadd_rn(__fadd_rn(__fmul_rn(R00, xw), __fmul_rn(R01, yw)), __fmul_rn(R02, zw)), t0);
        const float Yc = __fadd_rn(__fadd_rn(__fadd_rn(__fmul_rn(R10, xw), __fmul_rn(R11, yw)), __fmul_rn(R12, zw)), t1);
        const float Zc = __fadd_rn(__fadd_rn(__fadd_rn(__fmul_rn(R20, xw), __fmul_rn(R21, yw)), __fmul_rn(R22, zw)), t2);
        const float iu = __fdiv_rn(Xc, Zc);
        const float iv = __fdiv_rn(Yc, Zc);
        const float su = __fadd_rn(__fmul_rn(iu, fx), cx);
        const float sv = __fadd_rn(__fmul_rn(iv, fy), cy);
        const float unorm = __fsub_rn(__fmul_rn(__fmul_rn(su, 1.0f / 256.0f), 2.0f), 1.0f);
        const float vnorm = __fsub_rn(__fmul_rn(__fmul_rn(sv, 1.0f / 256.0f), 2.0f), 1.0f);
        const float xf = __fsub_rn(__fmul_rn(__fmul_rn(__fadd_rn(unorm, 1.0f), 0.5f), 256.0f), 0.5f);
        const float yf = __fsub_rn(__fmul_rn(__fmul_rn(__fadd_rn(vnorm, 1.0f), 0.5f), 256.0f), 0.5f);
        const int px = (int)fminf(fmaxf(rintf(xf), 0.0f), 255.0f);
        const int py = (int)fminf(fmaxf(rintf(yf), 0.0f), 255.0f);
        const int lin = py * 256 + px;
        const float rd = dmv[lin];
        const float rs = smv[lin];
        const float n0 = nmv[lin];
        const float n1 = nmv[HW + lin];
        const float n2 = nmv[2 * HW + lin];
        const float cosd = __fadd_rn(__fadd_rn(__fmul_rn(rdx, n0), __fmul_rn(rdy, n1)), __fmul_rn(rdz, n2));
        const bool m = (rs != 0.0f) && (fabsf(__fsub_rn(rd, Zc)) < 0.05f) && (cosd <= 0.0f);
        float ptv = 0.0f;
        if (m) {   // exec-masked: skip erf+div when no lane in wave passes
          const float invv = __fdiv_rn(1.0f, __fmul_rn(rs, SQRT2));
          const float a1 = __fmul_rn(__fsub_rn(__fadd_rn(Zc, sshalf), rd), invv);
          const float a2 = __fmul_rn(__fsub_rn(__fsub_rn(Zc, sshalf), rd), invv);
          ptv = __fmul_rn(0.5f, fabsf(__fsub_rn(erf_xla(a1), erf_xla(a2))));
        }
        ptm[k] = fmaxf(ptm[k], ptv);
      }
    }
  }

  // ---------------- Phase B: block scan + moments (registers + tiny LDS) ------
  float lp = 1.0f;
  if (act) {
#pragma unroll
    for (int k = 0; k < KPT; ++k) lp = __fmul_rn(lp, __fsub_rn(1.0f, ptm[k]));
  }
  float inc = lp;
#pragma unroll
  for (int off = 1; off < 64; off <<= 1) {
    float o = __shfl_up(inc, off);
    if (lane >= off) inc *= o;
  }
  if (lane == 63) s_wtot[wid] = inc;
  __syncthreads();                                    // B1
  float pw = 1.0f;
  if (wid > 0) pw *= s_wtot[0];
  if (wid > 1) pw *= s_wtot[1];
  if (wid > 2) pw *= s_wtot[2];
  float exc = __shfl_up(inc, 1);
  if (lane == 0) exc = 1.0f;
  exc *= pw;

  float accO = 0.0f, accZO = 0.0f;
  bool anynz = false;
  if (act) {
    float run = exc;
#pragma unroll
    for (int k = 0; k < KPT; ++k) {
      float o = ptm[k] * run;
      accO += o;
      accZO += zcr[k] * o;
      anynz |= (o != 0.0f);
      run *= (1.0f - ptm[k]);
    }
  }
  accO = wave_sum(accO);
  accZO = wave_sum(accZO);
  const int anyw = __any(anynz) ? 1 : 0;
  if (lane == 0) { s_sO[wid] = accO; s_sZ[wid] = accZO; s_fl[wid] = anyw; }
  __syncthreads();                                    // B2
  const float tO = s_sO[0] + s_sO[1] + s_sO[2] + s_sO[3];
  const float tZ = s_sZ[0] + s_sZ[1] + s_sZ[2] + s_sZ[3];
  const bool raymask = (s_fl[0] | s_fl[1] | s_fl[2] | s_fl[3]) != 0;
  const float swd = (tO > 0.0f) ? tO : 1.0f;
  const float meanz = __fdiv_rn(tZ, swd);

  float accV = 0.0f;
  if (act) {
    float run = exc;
#pragma unroll
    for (int k = 0; k < KPT; ++k) {
      float o = ptm[k] * run;
      float d = zcr[k] - meanz;
      accV += o * d * d;
      run *= (1.0f - ptm[k]);
    }
  }
  accV = wave_sum(accV);
  if (lane == 0) s_sV[wid] = accV;
  __syncthreads();                                    // B3
  const float tV = s_sV[0] + s_sV[1] + s_sV[2] + s_sV[3];
  const float stdz = sqrtf(__fdiv_rn(tV, swd));

  // ---------------- Phase C: stable top-25, registers, 1 barrier/round --------
#pragma unroll 1
  for (int kk = 0; kk < N_S - N_G; ++kk) {
    float bv = -2.0f;
    int bi = 0x40000000;
    if (act) {
#pragma unroll
      for (int k = 0; k < KPT; ++k) {
        const int i = tid * 4 + k;
        const float vv = ptm[k];
        if (vv > bv || (vv == bv && i < bi)) { bv = vv; bi = i; }
      }
    }
#pragma unroll
    for (int off = 1; off < 64; off <<= 1) {
      float ov = __shfl_xor(bv, off);
      int oi = __shfl_xor(bi, off);
      if (ov > bv || (ov == bv && oi < bi)) { bv = ov; bi = oi; }
    }
    const int par = kk & 1;
    if (lane == 0) { s_cval[par][wid] = bv; s_cidx[par][wid] = bi; }
    __syncthreads();
    bv = s_cval[par][0]; bi = s_cidx[par][0];
#pragma unroll
    for (int w = 1; w < 4; ++w) {
      float ov = s_cval[par][w];
      int oi = s_cidx[par][w];
      if (ov > bv || (ov == bv && oi < bi)) { bv = ov; bi = oi; }
    }
    if (bv == 0.0f) break;      // uniform: remaining winners all zero -> zsel stays 0
    if (tid == (bi >> 2)) {     // owner clears its register copy, records z
      const int r = bi & 3;
      const float zk = (r == 0) ? zcr[0] : ((r == 1) ? zcr[1] : ((r == 2) ? zcr[2] : zcr[3]));
      s_zsel[kk] = zk;
      if (r == 0) ptm[0] = -1.0f;
      else if (r == 1) ptm[1] = -1.0f;
      else if (r == 2) ptm[2] = -1.0f;
      else ptm[3] = -1.0f;
    }
  }
  __syncthreads();   // orders final zsel writes; uniform exit

  // ---------------- Phase D/E: gaussian slots, sort, miss-fill, sort (wave 0) -
  if (wid == 0) {
    float sortv;
    if (lane < N_S - N_G) {
      sortv = s_zsel[lane];
    } else if (lane < N_S) {
      const float g = gn[(size_t)ray * N_G + (lane - (N_S - N_G))];
      sortv = raymask ? (g * stdz + meanz) : 0.0f;
    } else {
      sortv = INFINITY;
    }
    float z = bitonic64(sortv, lane);
    const bool miss = (lane < N_S) && (z == 0.0f);
    const int nmiss_raw = __popcll(__ballot(miss));
    const int nmiss = (nmiss_raw < 1) ? 1 : nmiss_raw;
    const float stepf = __fdiv_rn(__fsub_rn(farv, nearv), (float)nmiss);
    if (miss) {
      const float ufv = uf[(size_t)ray * N_S + lane];
      z = __fadd_rn(__fadd_rn(nearv, __fmul_rn((float)lane, stepf)), __fmul_rn(ufv, stepf));
    }
    z = bitonic64(z, lane);
    const float zn = __shfl_down(z, 1);
    const float delta = (lane == N_S - 1) ? (farv - z) : (zn - z);
    if (lane < N_S) { s_zarr[lane] = z; s_darr[lane] = delta; }
  }
  __syncthreads();

  // ---------------- Phase F1: MLP, all 4 waves (10 samples each) --------------
  {
    float w1r[24], b1r4[4], w2r[16];
#pragma unroll
    for (int m = 0; m < 4; ++m) {
      const int j = lane + 64 * m;
#pragma unroll
      for (int k = 0; k < 6; ++k) w1r[k * 4 + m] = s_w1[k * N_HID + j];
      b1r4[m] = s_b1v[j];
#pragma unroll
      for (int c = 0; c < 4; ++c) w2r[m * 4 + c] = s_w2[j * 4 + c];
    }
#pragma unroll 1
    for (int q = 0; q < 10; ++q) {
      const int s = wid * 10 + q;
      const float zq = s_zarr[s];
      const float px = ox + zq * dx;
      const float py = oy + zq * dy;
      const float pz = oz + zq * dz;
      float a0 = 0.0f, a1 = 0.0f, a2 = 0.0f, a3 = 0.0f;
#pragma unroll
      for (int m = 0; m < 4; ++m) {
        float h = b1r4[m];
        h = fmaf(px, w1r[0 * 4 + m], h);
        h = fmaf(py, w1r[1 * 4 + m], h);
        h = fmaf(pz, w1r[2 * 4 + m], h);
        h = fmaf(dx, w1r[3 * 4 + m], h);
        h = fmaf(dy, w1r[4 * 4 + m], h);
        h = fmaf(dz, w1r[5 * 4 + m], h);
        h = fmaxf(h, 0.0f);
        a0 = fmaf(h, w2r[m * 4 + 0], a0);
        a1 = fmaf(h, w2r[m * 4 + 1], a1);
        a2 = fmaf(h, w2r[m * 4 + 2], a2);
        a3 = fmaf(h, w2r[m * 4 + 3], a3);
      }
      a0 = wave_sum(a0);
      a1 = wave_sum(a1);
      a2 = wave_sum(a2);
      a3 = wave_sum(a3);
      if (lane == 0) {
        s_mlp4[s] = make_float4(a0 + s_b2v[0], a1 + s_b2v[1], a2 + s_b2v[2], a3 + s_b2v[3]);
      }
    }
  }
  __syncthreads();

  // ---------------- Phase F2: composite + output (wave 0) ---------------------
  if (wid == 0) {
    float alpha = 0.0f, r0 = 0.0f, r1 = 0.0f, r2 = 0.0f, zl = 0.0f;
    float factor = 1.0f;
    if (lane < N_S) {
      zl = s_zarr[lane];
      const float dl = s_darr[lane];
      const float4 o4 = s_mlp4[lane];
      r0 = o4.x; r1 = o4.y; r2 = o4.z;
      const float rsig = fmaxf(o4.w, 0.0f);
      alpha = 1.0f - expf(-dl * rsig);
      factor = (1.0f - alpha) + 1e-10f;
    }
    float incp = factor;
#pragma unroll
    for (int off = 1; off < 64; off <<= 1) {
      float o = __shfl_up(incp, off);
      if (lane >= off) incp *= o;
    }
    float T = __shfl_up(incp, 1);
    if (lane == 0) T = 1.0f;

    const float w = (lane < N_S) ? alpha * T : 0.0f;
    const float wz = (lane < N_S) ? w * zl : 0.0f;
    const float wr0 = (lane < N_S) ? w * r0 : 0.0f;
    const float wr1 = (lane < N_S) ? w * r1 : 0.0f;
    const float wr2 = (lane < N_S) ? w * r2 : 0.0f;

    const float wsum = wave_sum(w);
    const float dsum = wave_sum(wz);
    const float c0s = wave_sum(wr0);
    const float c1s = wave_sum(wr1);
    const float c2s = wave_sum(wr2);

    if (lane < N_S) out[(size_t)ray * N_S + lane] = w;
    if (lane == 0) {
      float* rgbo = out + (size_t)N_SB * N_R * N_S + (size_t)ray * 3;
      rgbo[0] = (c0s + 1.0f) - wsum;
      rgbo[1] = (c1s + 1.0f) - wsum;
      rgbo[2] = (c2s + 1.0f) - wsum;
      out[(size_t)N_SB * N_R * N_S + (size_t)N_SB * N_R * 3 + ray] = dsum;
    }
  }
}

extern "C" void kernel_launch(void* const* d_in, const int* in_sizes, int n_in,
                              void* d_out, int out_size, void* d_ws, size_t ws_size,
                              hipStream_t stream) {
  const float* rays  = (const float*)d_in[0];
  const float* poses = (const float*)d_in[1];
  const float* focal = (const float*)d_in[2];
  const float* cvec  = (const float*)d_in[3];
  const float* dmap  = (const float*)d_in[4];
  const float* smap  = (const float*)d_in[5];
  const float* nmap  = (const float*)d_in[6];
  const float* W1p   = (const float*)d_in[7];
  const float* b1p   = (const float*)d_in[8];
  const float* W2p   = (const float*)d_in[9];
  const float* b2p   = (const float*)d_in[10];
  const float* ucp   = (const float*)d_in[11];
  const float* gnp   = (const float*)d_in[12];
  const float* ufp   = (const float*)d_in[13];
  float* outp = (float*)d_out;

  dim3 grid(N_SB * N_R);   // one ray per block
  dim3 block(256);
  nerf_all<<<grid, block, 0, stream>>>(rays, poses, focal, cvec, dmap, smap, nmap,
                                       W1p, b1p, W2p, b2p, ucp, gnp, ufp, outp);
}

// Round 3
// 165.942 us; speedup vs baseline: 1.3240x; 1.0673x over previous
//
#include <hip/hip_runtime.h>
#include <math.h>

#define N_SB 2
#define N_V  3
#define N_R  2048
#define N_C  1000
#define N_S  40
#define N_G  15
#define N_HID 256
#define HW 65536

__device__ __forceinline__ float wave_sum(float v) {
#pragma unroll
  for (int off = 32; off > 0; off >>= 1) v += __shfl_xor(v, off);
  return v;
}

// XLA/Eigen f32 erf: rational poly in x^2, clamp to +-erfinv(1-2^-23).
// Must stay bit-identical to rounds 1/2 (pt feeds discrete top-k selection).
__device__ __forceinline__ float erf_xla(float x) {
  const float c = 3.832506856900711f;
  x = fminf(fmaxf(x, -c), c);
  float x2 = __fmul_rn(x, x);
  float p = 0.00022905065861350646f;
  p = __fadd_rn(__fmul_rn(p, x2), 0.0034082910107109506f);
  p = __fadd_rn(__fmul_rn(p, x2), 0.050955695062380861f);
  p = __fadd_rn(__fmul_rn(p, x2), 0.18520832239976145f);
  p = __fadd_rn(__fmul_rn(p, x2), 1.128379143519084f);
  float q = -1.1791602954361697e-7f;
  q = __fadd_rn(__fmul_rn(q, x2), 0.000023547966471313185f);
  q = __fadd_rn(__fmul_rn(q, x2), 0.0010179625278914885f);
  q = __fadd_rn(__fmul_rn(q, x2), 0.014070470171167667f);
  q = __fadd_rn(__fmul_rn(q, x2), 0.11098505178285362f);
  q = __fadd_rn(__fmul_rn(q, x2), 0.49746925110067538f);
  q = __fadd_rn(__fmul_rn(q, x2), 1.0f);
  return __fdiv_rn(__fmul_rn(x, p), q);
}

__device__ __forceinline__ float bitonic64(float v, int lane) {
#pragma unroll
  for (int k = 2; k <= 64; k <<= 1) {
#pragma unroll
    for (int j = k >> 1; j >= 1; j >>= 1) {
      float o = __shfl_xor(v, j);
      bool up = ((lane & k) == 0);
      bool lower = ((lane & j) == 0);
      v = (lower == up) ? fminf(v, o) : fmaxf(v, o);
    }
  }
  return v;
}

__global__ __launch_bounds__(256, 4)
void nerf_all(const float* __restrict__ rays, const float* __restrict__ poses,
              const float* __restrict__ focal, const float* __restrict__ cvec,
              const float* __restrict__ dmap, const float* __restrict__ smap,
              const float* __restrict__ nmap, const float* __restrict__ W1,
              const float* __restrict__ b1, const float* __restrict__ W2,
              const float* __restrict__ b2, const float* __restrict__ uc,
              const float* __restrict__ gn, const float* __restrict__ uf,
              float* __restrict__ out)
{
  __shared__ __align__(16) float s_pt[1024];
  __shared__ __align__(16) float s_zc[1024];
  __shared__ float s_cv[100];
  __shared__ int   s_ci[100];
  __shared__ float s_cz[100];
  __shared__ float s_zsel[32];
  __shared__ float s_wtot[4], s_sO[4], s_sZ[4], s_sV[4];
  __shared__ int   s_fl[4];
  __shared__ float s_zarr[N_S], s_darr[N_S];
  __shared__ float s_mlp[N_S * 4];

  const int tid = threadIdx.x;
  const int wid = tid >> 6;
  const int lane = tid & 63;
  const int ray = blockIdx.x;       // one ray per block
  const int sb = ray >> 11;

  // init candidate/zsel slots (ordered vs later writes/reads by barrier #1)
  if (tid < 100) { s_cv[tid] = 0.0f; s_ci[tid] = 0x40000000; s_cz[tid] = 0.0f; }
  if (tid < 32) s_zsel[tid] = 0.0f;

  const float* rp = rays + (size_t)ray * 8;   // uniform per block -> SGPRs
  const float ox = rp[0], oy = rp[1], oz = rp[2];
  const float dx = rp[3], dy = rp[4], dz = rp[5];
  const float nearv = rp[6], farv = rp[7];

  const float lindelta = 0.999f / 999.0f;
  const float ssv = __fdiv_rn(__fsub_rn(farv, nearv), 1000.0f);
  const float sshalf = __fmul_rn(ssv, 0.5f);
  const float SQRT2 = 1.41421356237309515f;

  // ---------------- Phase A: lane-adjacent samples, pt -> LDS ----------------
  float zg[4] = {0.0f, 0.0f, 0.0f, 0.0f};
  float ptg[4] = {0.0f, 0.0f, 0.0f, 0.0f};
#pragma unroll
  for (int cch = 0; cch < 4; ++cch) {
    const int i = cch * 256 + tid;
    if (i < N_C) {
      const float u = uc[(size_t)ray * N_C + i];
      const float zs = __fadd_rn(__fmul_rn((float)i, lindelta), __fmul_rn(u, 0.001f));
      const float zc = __fadd_rn(__fmul_rn(nearv, __fsub_rn(1.0f, zs)), __fmul_rn(farv, zs));
      zg[cch] = zc;
      s_zc[i] = zc;
    }
  }

#pragma unroll
  for (int v = 0; v < N_V; ++v) {
    const float* pp = poses + (size_t)(sb * N_V + v) * 16;
    const float R00 = pp[0], R01 = pp[1], R02 = pp[2], t0 = pp[3];
    const float R10 = pp[4], R11 = pp[5], R12 = pp[6], t1 = pp[7];
    const float R20 = pp[8], R21 = pp[9], R22 = pp[10], t2 = pp[11];
    const float fx = focal[(sb * N_V + v) * 2 + 0];
    const float fy = focal[(sb * N_V + v) * 2 + 1];
    const float cx = cvec[(sb * N_V + v) * 2 + 0];
    const float cy = cvec[(sb * N_V + v) * 2 + 1];
    const float rdx = __fadd_rn(__fadd_rn(__fmul_rn(R00, dx), __fmul_rn(R01, dy)), __fmul_rn(R02, dz));
    const float rdy = __fadd_rn(__fadd_rn(__fmul_rn(R10, dx), __fmul_rn(R11, dy)), __fmul_rn(R12, dz));
    const float rdz = __fadd_rn(__fadd_rn(__fmul_rn(R20, dx), __fmul_rn(R21, dy)), __fmul_rn(R22, dz));
    const float* dmv = dmap + (size_t)(sb * N_V + v) * HW;
    const float* smv = smap + (size_t)(sb * N_V + v) * HW;
    const float* nmv = nmap + (size_t)(sb * N_V + v) * 3 * HW;

#pragma unroll
    for (int cch = 0; cch < 4; ++cch) {
      const int i = cch * 256 + tid;
      if (i < N_C) {
        const float zc = zg[cch];
        const float xw = __fadd_rn(ox, __fmul_rn(zc, dx));
        const float yw = __fadd_rn(oy, __fmul_rn(zc, dy));
        const float zw = __fadd_rn(oz, __fmul_rn(zc, dz));
        const float Xc = __fadd_rn(__fadd_rn(__fadd_rn(__fmul_rn(R00, xw), __fmul_rn(R01, yw)), __fmul_rn(R02, zw)), t0);
        const float Yc = __fadd_rn(__fadd_rn(__fadd_rn(__fmul_rn(R10, xw), __fmul_rn(R11, yw)), __fmul_rn(R12, zw)), t1);
        const float Zc = __fadd_rn(__fadd_rn(__fadd_rn(__fmul_rn(R20, xw), __fmul_rn(R21, yw)), __fmul_rn(R22, zw)), t2);
        const float iu = __fdiv_rn(Xc, Zc);
        const float iv = __fdiv_rn(Yc, Zc);
        const float su = __fadd_rn(__fmul_rn(iu, fx), cx);
        const float sv = __fadd_rn(__fmul_rn(iv, fy), cy);
        const float unorm = __fsub_rn(__fmul_rn(__fmul_rn(su, 1.0f / 256.0f), 2.0f), 1.0f);
        const float vnorm = __fsub_rn(__fmul_rn(__fmul_rn(sv, 1.0f / 256.0f), 2.0f), 1.0f);
        const float xf = __fsub_rn(__fmul_rn(__fmul_rn(__fadd_rn(unorm, 1.0f), 0.5f), 256.0f), 0.5f);
        const float yf = __fsub_rn(__fmul_rn(__fmul_rn(__fadd_rn(vnorm, 1.0f), 0.5f), 256.0f), 0.5f);
        const int px = (int)fminf(fmaxf(rintf(xf), 0.0f), 255.0f);
        const int py = (int)fminf(fmaxf(rintf(yf), 0.0f), 255.0f);
        const int lin = py * 256 + px;
        const float rd = dmv[lin];
        const float rs = smv[lin];
        const float n0 = nmv[lin];
        const float n1 = nmv[HW + lin];
        const float n2 = nmv[2 * HW + lin];
        const float cosd = __fadd_rn(__fadd_rn(__fmul_rn(rdx, n0), __fmul_rn(rdy, n1)), __fmul_rn(rdz, n2));
        const bool m = (rs != 0.0f) && (fabsf(__fsub_rn(rd, Zc)) < 0.05f) && (cosd <= 0.0f);
        float ptv = 0.0f;
        if (m) {   // exec-masked: adjacent-lane samples fail together -> real skips
          const float invv = __fdiv_rn(1.0f, __fmul_rn(rs, SQRT2));
          const float a1 = __fmul_rn(__fsub_rn(__fadd_rn(Zc, sshalf), rd), invv);
          const float a2 = __fmul_rn(__fsub_rn(__fsub_rn(Zc, sshalf), rd), invv);
          ptv = __fmul_rn(0.5f, fabsf(__fsub_rn(erf_xla(a1), erf_xla(a2))));
        }
        ptg[cch] = fmaxf(ptg[cch], ptv);
      }
    }
  }
#pragma unroll
  for (int cch = 0; cch < 4; ++cch) {
    const int i = cch * 256 + tid;
    if (i < N_C) s_pt[i] = ptg[cch];
  }
  __syncthreads();                                    // #1

  // ---------------- ownership switch: thread owns 4 consecutive samples ------
  const bool act = (tid < 250);
  float ptm[4] = {0.0f, 0.0f, 0.0f, 0.0f};
  float zcr[4] = {0.0f, 0.0f, 0.0f, 0.0f};
  if (act) {
    const float4 p4 = *(const float4*)&s_pt[tid * 4];
    ptm[0] = p4.x; ptm[1] = p4.y; ptm[2] = p4.z; ptm[3] = p4.w;
    const float4 z4 = *(const float4*)&s_zc[tid * 4];
    zcr[0] = z4.x; zcr[1] = z4.y; zcr[2] = z4.z; zcr[3] = z4.w;
  }

  // ---------------- Phase B: block scan + moments ----------------------------
  float lp = 1.0f;
  if (act) {
#pragma unroll
    for (int k = 0; k < 4; ++k) lp = __fmul_rn(lp, __fsub_rn(1.0f, ptm[k]));
  }
  float inc = lp;
#pragma unroll
  for (int off = 1; off < 64; off <<= 1) {
    float o = __shfl_up(inc, off);
    if (lane >= off) inc *= o;
  }
  if (lane == 63) s_wtot[wid] = inc;
  __syncthreads();                                    // #2
  float pw = 1.0f;
  if (wid > 0) pw *= s_wtot[0];
  if (wid > 1) pw *= s_wtot[1];
  if (wid > 2) pw *= s_wtot[2];
  float exc = __shfl_up(inc, 1);
  if (lane == 0) exc = 1.0f;
  exc *= pw;

  float accO = 0.0f, accZO = 0.0f;
  bool anynz = false;
  if (act) {
    float run = exc;
#pragma unroll
    for (int k = 0; k < 4; ++k) {
      float o = ptm[k] * run;
      accO += o;
      accZO += zcr[k] * o;
      anynz |= (o != 0.0f);
      run *= (1.0f - ptm[k]);
    }
  }
  accO = wave_sum(accO);
  accZO = wave_sum(accZO);
  const int anyw = __any(anynz) ? 1 : 0;
  if (lane == 0) { s_sO[wid] = accO; s_sZ[wid] = accZO; s_fl[wid] = anyw; }
  __syncthreads();                                    // #3
  const float tO = s_sO[0] + s_sO[1] + s_sO[2] + s_sO[3];
  const float tZ = s_sZ[0] + s_sZ[1] + s_sZ[2] + s_sZ[3];
  const bool raymask = (s_fl[0] | s_fl[1] | s_fl[2] | s_fl[3]) != 0;
  const float swd = (tO > 0.0f) ? tO : 1.0f;
  const float meanz = __fdiv_rn(tZ, swd);

  float accV = 0.0f;
  if (act) {
    float run = exc;
#pragma unroll
    for (int k = 0; k < 4; ++k) {
      float o = ptm[k] * run;
      float d = zcr[k] - meanz;
      accV += o * d * d;
      run *= (1.0f - ptm[k]);
    }
  }
  accV = wave_sum(accV);
  if (lane == 0) s_sV[wid] = accV;
  __syncthreads();                                    // #4
  const float tV = s_sV[0] + s_sV[1] + s_sV[2] + s_sV[3];
  const float stdz = sqrtf(__fdiv_rn(tV, swd));

  // ---------------- Phase C1: per-wave stable top-25, NO block barriers ------
  const int cbase = wid * 25;
#pragma unroll 1
  for (int kk = 0; kk < 25; ++kk) {
    float bv = -2.0f;
    int bi = 0x40000000;
    if (act) {
#pragma unroll
      for (int k = 0; k < 4; ++k) {
        // ascending k => ascending idx: strict > keeps smallest index on ties
        if (ptm[k] > bv) { bv = ptm[k]; bi = tid * 4 + k; }
      }
    }
#pragma unroll
    for (int off = 1; off < 64; off <<= 1) {
      float ov = __shfl_xor(bv, off);
      int oi = __shfl_xor(bi, off);
      if (ov > bv || (ov == bv && oi < bi)) { bv = ov; bi = oi; }
    }
    if (bv <= 0.0f) break;   // wave-uniform early exit; rest stay at init (val 0)
    if (tid == (bi >> 2)) {  // owner records candidate and clears its copy
      s_cv[cbase + kk] = bv;
      s_ci[cbase + kk] = bi;
      const int r = bi & 3;
      float zk;
      if (r == 0)      { zk = zcr[0]; ptm[0] = -1.0f; }
      else if (r == 1) { zk = zcr[1]; ptm[1] = -1.0f; }
      else if (r == 2) { zk = zcr[2]; ptm[2] = -1.0f; }
      else             { zk = zcr[3]; ptm[3] = -1.0f; }
      s_cz[cbase + kk] = zk;
    }
  }
  __syncthreads();                                    // #5

  // ---------------- Phase C2: wave-0 merge of <=100 candidates ---------------
  if (wid == 0) {
    float c0v = s_cv[lane];
    int   c0i = s_ci[lane];
    float c0z = s_cz[lane];
    float c1v = -2.0f; int c1i = 0x40000000; float c1z = 0.0f;
    if (lane + 64 < 100) { c1v = s_cv[lane + 64]; c1i = s_ci[lane + 64]; c1z = s_cz[lane + 64]; }
#pragma unroll 1
    for (int kk = 0; kk < 25; ++kk) {
      float bv = c0v; int bi = c0i; float bz = c0z;
      if (c1v > bv || (c1v == bv && c1i < bi)) { bv = c1v; bi = c1i; bz = c1z; }
#pragma unroll
      for (int off = 1; off < 64; off <<= 1) {
        float ov = __shfl_xor(bv, off);
        int oi = __shfl_xor(bi, off);
        float oz = __shfl_xor(bz, off);
        if (ov > bv || (ov == bv && oi < bi)) { bv = ov; bi = oi; bz = oz; }
      }
      if (bv <= 0.0f) break;              // remaining zsel stay 0 (== reference)
      if (lane == 0) s_zsel[kk] = bz;     // same-wave LDS RAW: in-order, no barrier
      if (c0i == bi) c0v = -1.0f;         // idx unique: exactly the winner clears
      if (c1i == bi) c1v = -1.0f;
    }
  }

  // ---------------- Phase D/E: gaussian slots, sort, fill, sort (wave 0) -----
  if (wid == 0) {
    float sortv;
    if (lane < N_S - N_G) {
      sortv = s_zsel[lane];
    } else if (lane < N_S) {
      const float g = gn[(size_t)ray * N_G + (lane - (N_S - N_G))];
      sortv = raymask ? (g * stdz + meanz) : 0.0f;
    } else {
      sortv = INFINITY;
    }
    float z = bitonic64(sortv, lane);
    const bool miss = (lane < N_S) && (z == 0.0f);
    const int nmiss_raw = __popcll(__ballot(miss));
    const int nmiss = (nmiss_raw < 1) ? 1 : nmiss_raw;
    const float stepf = __fdiv_rn(__fsub_rn(farv, nearv), (float)nmiss);
    if (miss) {
      const float ufv = uf[(size_t)ray * N_S + lane];
      z = __fadd_rn(__fadd_rn(nearv, __fmul_rn((float)lane, stepf)), __fmul_rn(ufv, stepf));
    }
    z = bitonic64(z, lane);
    const float zn = __shfl_down(z, 1);
    const float delta = (lane == N_S - 1) ? (farv - z) : (zn - z);
    if (lane < N_S) { s_zarr[lane] = z; s_darr[lane] = delta; }
  }
  __syncthreads();                                    // #6

  // ---------------- Phase F1: MLP, 10 samples/wave, multi-channel reduce -----
  {
    const float b2r = (lane < 4) ? b2[lane] : 0.0f;
    float w1r[24], b1r[4], w2r[16];
#pragma unroll
    for (int m = 0; m < 4; ++m) {
      const int j = lane + 64 * m;
#pragma unroll
      for (int k = 0; k < 6; ++k) w1r[k * 4 + m] = W1[k * N_HID + j];
      b1r[m] = b1[j];
      const float4 w2v = *(const float4*)(W2 + (size_t)j * 4);
      w2r[m * 4 + 0] = w2v.x; w2r[m * 4 + 1] = w2v.y;
      w2r[m * 4 + 2] = w2v.z; w2r[m * 4 + 3] = w2v.w;
    }
#pragma unroll 1
    for (int q = 0; q < 10; ++q) {
      const int s = wid * 10 + q;
      const float zq = s_zarr[s];
      const float px = ox + zq * dx;
      const float py = oy + zq * dy;
      const float pz = oz + zq * dz;
      float a0 = 0.0f, a1 = 0.0f, a2 = 0.0f, a3 = 0.0f;
#pragma unroll
      for (int m = 0; m < 4; ++m) {
        float h = b1r[m];
        h = fmaf(px, w1r[0 * 4 + m], h);
        h = fmaf(py, w1r[1 * 4 + m], h);
        h = fmaf(pz, w1r[2 * 4 + m], h);
        h = fmaf(dx, w1r[3 * 4 + m], h);
        h = fmaf(dy, w1r[4 * 4 + m], h);
        h = fmaf(dz, w1r[5 * 4 + m], h);
        h = fmaxf(h, 0.0f);
        a0 = fmaf(h, w2r[m * 4 + 0], a0);
        a1 = fmaf(h, w2r[m * 4 + 1], a1);
        a2 = fmaf(h, w2r[m * 4 + 2], a2);
        a3 = fmaf(h, w2r[m * 4 + 3], a3);
      }
      // multi-channel butterfly: lane (l&3) ends with channel (l&3) total
      const float s0 = __shfl_xor(a0, 1), s1 = __shfl_xor(a1, 1);
      const float s2 = __shfl_xor(a2, 1), s3 = __shfl_xor(a3, 1);
      const float m0 = (lane & 1) ? (a1 + s1) : (a0 + s0);
      const float m1 = (lane & 1) ? (a3 + s3) : (a2 + s2);
      const float t0 = __shfl_xor(m0, 2), t1 = __shfl_xor(m1, 2);
      float r = (lane & 2) ? (m1 + t1) : (m0 + t0);
#pragma unroll
      for (int off = 4; off < 64; off <<= 1) r += __shfl_xor(r, off);
      if (lane < 4) s_mlp[s * 4 + lane] = r + b2r;
    }
  }
  __syncthreads();                                    // #7

  // ---------------- Phase F2: composite + output (wave 0) --------------------
  if (wid == 0) {
    float alpha = 0.0f, r0 = 0.0f, r1 = 0.0f, r2 = 0.0f, zl = 0.0f;
    float factor = 1.0f;
    if (lane < N_S) {
      zl = s_zarr[lane];
      const float dl = s_darr[lane];
      r0 = s_mlp[lane * 4 + 0];
      r1 = s_mlp[lane * 4 + 1];
      r2 = s_mlp[lane * 4 + 2];
      const float rsig = fmaxf(s_mlp[lane * 4 + 3], 0.0f);
      alpha = 1.0f - expf(-dl * rsig);
      factor = (1.0f - alpha) + 1e-10f;
    }
    float incp = factor;
#pragma unroll
    for (int off = 1; off < 64; off <<= 1) {
      float o = __shfl_up(incp, off);
      if (lane >= off) incp *= o;
    }
    float T = __shfl_up(incp, 1);
    if (lane == 0) T = 1.0f;

    const float w = (lane < N_S) ? alpha * T : 0.0f;
    const float wz = (lane < N_S) ? w * zl : 0.0f;
    const float wr0 = (lane < N_S) ? w * r0 : 0.0f;
    const float wr1 = (lane < N_S) ? w * r1 : 0.0f;
    const float wr2 = (lane < N_S) ? w * r2 : 0.0f;

    const float wsum = wave_sum(w);
    const float dsum = wave_sum(wz);
    const float c0s = wave_sum(wr0);
    const float c1s = wave_sum(wr1);
    const float c2s = wave_sum(wr2);

    if (lane < N_S) out[(size_t)ray * N_S + lane] = w;
    if (lane == 0) {
      float* rgbo = out + (size_t)N_SB * N_R * N_S + (size_t)ray * 3;
      rgbo[0] = (c0s + 1.0f) - wsum;
      rgbo[1] = (c1s + 1.0f) - wsum;
      rgbo[2] = (c2s + 1.0f) - wsum;
      out[(size_t)N_SB * N_R * N_S + (size_t)N_SB * N_R * 3 + ray] = dsum;
    }
  }
}

extern "C" void kernel_launch(void* const* d_in, const int* in_sizes, int n_in,
                              void* d_out, int out_size, void* d_ws, size_t ws_size,
                              hipStream_t stream) {
  const float* rays  = (const float*)d_in[0];
  const float* poses = (const float*)d_in[1];
  const float* focal = (const float*)d_in[2];
  const float* cvec  = (const float*)d_in[3];
  const float* dmap  = (const float*)d_in[4];
  const float* smap  = (const float*)d_in[5];
  const float* nmap  = (const float*)d_in[6];
  const float* W1p   = (const float*)d_in[7];
  const float* b1p   = (const float*)d_in[8];
  const float* W2p   = (const float*)d_in[9];
  const float* b2p   = (const float*)d_in[10];
  const float* ucp   = (const float*)d_in[11];
  const float* gnp   = (const float*)d_in[12];
  const float* ufp   = (const float*)d_in[13];
  float* outp = (float*)d_out;

  dim3 grid(N_SB * N_R);   // one ray per block
  dim3 block(256);
  nerf_all<<<grid, block, 0, stream>>>(rays, poses, focal, cvec, dmap, smap, nmap,
                                       W1p, b1p, W2p, b2p, ucp, gnp, ufp, outp);
}

// Round 4
// 155.539 us; speedup vs baseline: 1.4126x; 1.0669x over previous
//
#include <hip/hip_runtime.h>
#include <math.h>

#define N_SB 2
#define N_V  3
#define N_R  2048
#define N_C  1000
#define N_S  40
#define N_G  15
#define N_HID 256
#define HW 65536

__device__ __forceinline__ float wave_sum(float v) {
#pragma unroll
  for (int off = 32; off > 0; off >>= 1) v += __shfl_xor(v, off);
  return v;
}

// XLA/Eigen f32 erf: rational poly in x^2, clamp to +-erfinv(1-2^-23).
// Must stay bit-identical across rounds (pt feeds discrete top-k selection).
__device__ __forceinline__ float erf_xla(float x) {
  const float c = 3.832506856900711f;
  x = fminf(fmaxf(x, -c), c);
  float x2 = __fmul_rn(x, x);
  float p = 0.00022905065861350646f;
  p = __fadd_rn(__fmul_rn(p, x2), 0.0034082910107109506f);
  p = __fadd_rn(__fmul_rn(p, x2), 0.050955695062380861f);
  p = __fadd_rn(__fmul_rn(p, x2), 0.18520832239976145f);
  p = __fadd_rn(__fmul_rn(p, x2), 1.128379143519084f);
  float q = -1.1791602954361697e-7f;
  q = __fadd_rn(__fmul_rn(q, x2), 0.000023547966471313185f);
  q = __fadd_rn(__fmul_rn(q, x2), 0.0010179625278914885f);
  q = __fadd_rn(__fmul_rn(q, x2), 0.014070470171167667f);
  q = __fadd_rn(__fmul_rn(q, x2), 0.11098505178285362f);
  q = __fadd_rn(__fmul_rn(q, x2), 0.49746925110067538f);
  q = __fadd_rn(__fmul_rn(q, x2), 1.0f);
  return __fdiv_rn(__fmul_rn(x, p), q);
}

__device__ __forceinline__ float bitonic64(float v, int lane) {
#pragma unroll
  for (int k = 2; k <= 64; k <<= 1) {
#pragma unroll
    for (int j = k >> 1; j >= 1; j >>= 1) {
      float o = __shfl_xor(v, j);
      bool up = ((lane & k) == 0);
      bool lower = ((lane & j) == 0);
      v = (lower == up) ? fminf(v, o) : fmaxf(v, o);
    }
  }
  return v;
}

__global__ __launch_bounds__(256, 4)
void nerf_all(const float* __restrict__ rays, const float* __restrict__ poses,
              const float* __restrict__ focal, const float* __restrict__ cvec,
              const float* __restrict__ dmap, const float* __restrict__ smap,
              const float* __restrict__ nmap, const float* __restrict__ W1,
              const float* __restrict__ b1, const float* __restrict__ W2,
              const float* __restrict__ b2, const float* __restrict__ uc,
              const float* __restrict__ gn, const float* __restrict__ uf,
              float* __restrict__ out)
{
  __shared__ __align__(16) float s_pt[1024];
  __shared__ __align__(16) float s_zc[1024];
  __shared__ float s_cv[100];
  __shared__ int   s_ci[100];
  __shared__ float s_cz[100];
  __shared__ float s_zsel[32];
  __shared__ float s_wtot[4], s_sO[4], s_sZ[4], s_sV[4];
  __shared__ int   s_fl[4];
  __shared__ float s_zarr[N_S], s_darr[N_S];
  __shared__ float s_mlp[N_S * 4];

  const int tid = threadIdx.x;
  const int wid = tid >> 6;
  const int lane = tid & 63;
  const int ray = blockIdx.x;       // one ray per block
  const int sb = ray >> 11;

  // init candidate/zsel slots (ordered vs later writes/reads by barrier #1)
  if (tid < 100) { s_cv[tid] = 0.0f; s_ci[tid] = 0x40000000; s_cz[tid] = 0.0f; }
  if (tid < 32) s_zsel[tid] = 0.0f;

  const float* rp = rays + (size_t)ray * 8;   // uniform per block -> SGPRs
  const float ox = rp[0], oy = rp[1], oz = rp[2];
  const float dx = rp[3], dy = rp[4], dz = rp[5];
  const float nearv = rp[6], farv = rp[7];

  const float lindelta = 0.999f / 999.0f;
  const float ssv = __fdiv_rn(__fsub_rn(farv, nearv), 1000.0f);
  const float sshalf = __fmul_rn(ssv, 0.5f);
  const float SQRT2 = 1.41421356237309515f;

  // ---------------- Phase A: lane-adjacent samples, depth-gated gathers ------
  float zg[4] = {0.0f, 0.0f, 0.0f, 0.0f};
  float ptg[4] = {0.0f, 0.0f, 0.0f, 0.0f};
#pragma unroll
  for (int cch = 0; cch < 4; ++cch) {
    const int i = cch * 256 + tid;
    if (i < N_C) {
      const float u = uc[(size_t)ray * N_C + i];
      const float zs = __fadd_rn(__fmul_rn((float)i, lindelta), __fmul_rn(u, 0.001f));
      const float zc = __fadd_rn(__fmul_rn(nearv, __fsub_rn(1.0f, zs)), __fmul_rn(farv, zs));
      zg[cch] = zc;
      s_zc[i] = zc;
    }
  }

#pragma unroll 1
  for (int v = 0; v < N_V; ++v) {
    const float* pp = poses + (size_t)(sb * N_V + v) * 16;
    const float R00 = pp[0], R01 = pp[1], R02 = pp[2], t0 = pp[3];
    const float R10 = pp[4], R11 = pp[5], R12 = pp[6], t1 = pp[7];
    const float R20 = pp[8], R21 = pp[9], R22 = pp[10], t2 = pp[11];
    const float fx = focal[(sb * N_V + v) * 2 + 0];
    const float fy = focal[(sb * N_V + v) * 2 + 1];
    const float cx = cvec[(sb * N_V + v) * 2 + 0];
    const float cy = cvec[(sb * N_V + v) * 2 + 1];
    const float rdx = __fadd_rn(__fadd_rn(__fmul_rn(R00, dx), __fmul_rn(R01, dy)), __fmul_rn(R02, dz));
    const float rdy = __fadd_rn(__fadd_rn(__fmul_rn(R10, dx), __fmul_rn(R11, dy)), __fmul_rn(R12, dz));
    const float rdz = __fadd_rn(__fadd_rn(__fmul_rn(R20, dx), __fmul_rn(R21, dy)), __fmul_rn(R22, dz));
    const float* dmv = dmap + (size_t)(sb * N_V + v) * HW;
    const float* smv = smap + (size_t)(sb * N_V + v) * HW;
    const float* nmv = nmap + (size_t)(sb * N_V + v) * 3 * HW;

    // stage 1: project all 4 chunks, issue all 4 rd loads (pipelined).
    // pixel clamp guarantees lin in [0,65535] even for the i>=N_C tail
    // lanes (zg=0 -> finite proj) so the loads are unconditionally safe.
    int   linv[4];
    float Zcv[4];
    float rdv[4];
#pragma unroll
    for (int cch = 0; cch < 4; ++cch) {
      const float zc = zg[cch];
      const float xw = __fadd_rn(ox, __fmul_rn(zc, dx));
      const float yw = __fadd_rn(oy, __fmul_rn(zc, dy));
      const float zw = __fadd_rn(oz, __fmul_rn(zc, dz));
      const float Xc = __fadd_rn(__fadd_rn(__fadd_rn(__fmul_rn(R00, xw), __fmul_rn(R01, yw)), __fmul_rn(R02, zw)), t0);
      const float Yc = __fadd_rn(__fadd_rn(__fadd_rn(__fmul_rn(R10, xw), __fmul_rn(R11, yw)), __fmul_rn(R12, zw)), t1);
      const float Zc = __fadd_rn(__fadd_rn(__fadd_rn(__fmul_rn(R20, xw), __fmul_rn(R21, yw)), __fmul_rn(R22, zw)), t2);
      const float iu = __fdiv_rn(Xc, Zc);
      const float iv = __fdiv_rn(Yc, Zc);
      const float su = __fadd_rn(__fmul_rn(iu, fx), cx);
      const float sv = __fadd_rn(__fmul_rn(iv, fy), cy);
      const float unorm = __fsub_rn(__fmul_rn(__fmul_rn(su, 1.0f / 256.0f), 2.0f), 1.0f);
      const float vnorm = __fsub_rn(__fmul_rn(__fmul_rn(sv, 1.0f / 256.0f), 2.0f), 1.0f);
      const float xf = __fsub_rn(__fmul_rn(__fmul_rn(__fadd_rn(unorm, 1.0f), 0.5f), 256.0f), 0.5f);
      const float yf = __fsub_rn(__fmul_rn(__fmul_rn(__fadd_rn(vnorm, 1.0f), 0.5f), 256.0f), 0.5f);
      const int px = (int)fminf(fmaxf(rintf(xf), 0.0f), 255.0f);
      const int py = (int)fminf(fmaxf(rintf(yf), 0.0f), 255.0f);
      linv[cch] = py * 256 + px;
      Zcv[cch] = Zc;
      rdv[cch] = dmv[linv[cch]];
    }

    // stage 2: depth-gate (~3% pass) -> remaining 4 gathers + erf only then.
    // mask = (rs!=0) & (|rd-Zc|<0.05) & (cosd<=0); gating on the middle term
    // first is exact (pt=0 when it fails) and needs only rd.
#pragma unroll
    for (int cch = 0; cch < 4; ++cch) {
      const int i = cch * 256 + tid;
      const float Zc = Zcv[cch];
      const float rd = rdv[cch];
      if (i < N_C && fabsf(__fsub_rn(rd, Zc)) < 0.05f) {
        const int lin = linv[cch];
        const float rs = smv[lin];
        const float n0 = nmv[lin];
        const float n1 = nmv[HW + lin];
        const float n2 = nmv[2 * HW + lin];
        const float cosd = __fadd_rn(__fadd_rn(__fmul_rn(rdx, n0), __fmul_rn(rdy, n1)), __fmul_rn(rdz, n2));
        if ((rs != 0.0f) && (cosd <= 0.0f)) {
          const float invv = __fdiv_rn(1.0f, __fmul_rn(rs, SQRT2));
          const float a1 = __fmul_rn(__fsub_rn(__fadd_rn(Zc, sshalf), rd), invv);
          const float a2 = __fmul_rn(__fsub_rn(__fsub_rn(Zc, sshalf), rd), invv);
          const float ptv = __fmul_rn(0.5f, fabsf(__fsub_rn(erf_xla(a1), erf_xla(a2))));
          ptg[cch] = fmaxf(ptg[cch], ptv);
        }
      }
    }
  }
#pragma unroll
  for (int cch = 0; cch < 4; ++cch) {
    const int i = cch * 256 + tid;
    if (i < N_C) s_pt[i] = ptg[cch];
  }
  __syncthreads();                                    // #1

  // ---------------- ownership switch: thread owns 4 consecutive samples ------
  const bool act = (tid < 250);
  float ptm[4] = {0.0f, 0.0f, 0.0f, 0.0f};
  float zcr[4] = {0.0f, 0.0f, 0.0f, 0.0f};
  if (act) {
    const float4 p4 = *(const float4*)&s_pt[tid * 4];
    ptm[0] = p4.x; ptm[1] = p4.y; ptm[2] = p4.z; ptm[3] = p4.w;
    const float4 z4 = *(const float4*)&s_zc[tid * 4];
    zcr[0] = z4.x; zcr[1] = z4.y; zcr[2] = z4.z; zcr[3] = z4.w;
  }

  // ---------------- Phase B: block scan + moments ----------------------------
  float lp = 1.0f;
  if (act) {
#pragma unroll
    for (int k = 0; k < 4; ++k) lp = __fmul_rn(lp, __fsub_rn(1.0f, ptm[k]));
  }
  float inc = lp;
#pragma unroll
  for (int off = 1; off < 64; off <<= 1) {
    float o = __shfl_up(inc, off);
    if (lane >= off) inc *= o;
  }
  if (lane == 63) s_wtot[wid] = inc;
  __syncthreads();                                    // #2
  float pw = 1.0f;
  if (wid > 0) pw *= s_wtot[0];
  if (wid > 1) pw *= s_wtot[1];
  if (wid > 2) pw *= s_wtot[2];
  float exc = __shfl_up(inc, 1);
  if (lane == 0) exc = 1.0f;
  exc *= pw;

  float accO = 0.0f, accZO = 0.0f;
  bool anynz = false;
  if (act) {
    float run = exc;
#pragma unroll
    for (int k = 0; k < 4; ++k) {
      float o = ptm[k] * run;
      accO += o;
      accZO += zcr[k] * o;
      anynz |= (o != 0.0f);
      run *= (1.0f - ptm[k]);
    }
  }
  accO = wave_sum(accO);
  accZO = wave_sum(accZO);
  const int anyw = __any(anynz) ? 1 : 0;
  if (lane == 0) { s_sO[wid] = accO; s_sZ[wid] = accZO; s_fl[wid] = anyw; }
  __syncthreads();                                    // #3
  const float tO = s_sO[0] + s_sO[1] + s_sO[2] + s_sO[3];
  const float tZ = s_sZ[0] + s_sZ[1] + s_sZ[2] + s_sZ[3];
  const bool raymask = (s_fl[0] | s_fl[1] | s_fl[2] | s_fl[3]) != 0;
  const float swd = (tO > 0.0f) ? tO : 1.0f;
  const float meanz = __fdiv_rn(tZ, swd);

  float accV = 0.0f;
  if (act) {
    float run = exc;
#pragma unroll
    for (int k = 0; k < 4; ++k) {
      float o = ptm[k] * run;
      float d = zcr[k] - meanz;
      accV += o * d * d;
      run *= (1.0f - ptm[k]);
    }
  }
  accV = wave_sum(accV);
  if (lane == 0) s_sV[wid] = accV;
  __syncthreads();                                    // #4
  const float tV = s_sV[0] + s_sV[1] + s_sV[2] + s_sV[3];
  const float stdz = sqrtf(__fdiv_rn(tV, swd));

  // ---------------- Phase C1: per-wave stable top-25, NO block barriers ------
  const int cbase = wid * 25;
#pragma unroll 1
  for (int kk = 0; kk < 25; ++kk) {
    float bv = -2.0f;
    int bi = 0x40000000;
    if (act) {
#pragma unroll
      for (int k = 0; k < 4; ++k) {
        // ascending k => ascending idx: strict > keeps smallest index on ties
        if (ptm[k] > bv) { bv = ptm[k]; bi = tid * 4 + k; }
      }
    }
#pragma unroll
    for (int off = 1; off < 64; off <<= 1) {
      float ov = __shfl_xor(bv, off);
      int oi = __shfl_xor(bi, off);
      if (ov > bv || (ov == bv && oi < bi)) { bv = ov; bi = oi; }
    }
    if (bv <= 0.0f) break;   // wave-uniform early exit; rest stay at init (val 0)
    if (tid == (bi >> 2)) {  // owner records candidate and clears its copy
      s_cv[cbase + kk] = bv;
      s_ci[cbase + kk] = bi;
      const int r = bi & 3;
      float zk;
      if (r == 0)      { zk = zcr[0]; ptm[0] = -1.0f; }
      else if (r == 1) { zk = zcr[1]; ptm[1] = -1.0f; }
      else if (r == 2) { zk = zcr[2]; ptm[2] = -1.0f; }
      else             { zk = zcr[3]; ptm[3] = -1.0f; }
      s_cz[cbase + kk] = zk;
    }
  }
  __syncthreads();                                    // #5

  // ---------------- Phase C2: wave-0 merge of <=100 candidates ---------------
  if (wid == 0) {
    float c0v = s_cv[lane];
    int   c0i = s_ci[lane];
    float c0z = s_cz[lane];
    float c1v = -2.0f; int c1i = 0x40000000; float c1z = 0.0f;
    if (lane + 64 < 100) { c1v = s_cv[lane + 64]; c1i = s_ci[lane + 64]; c1z = s_cz[lane + 64]; }
#pragma unroll 1
    for (int kk = 0; kk < 25; ++kk) {
      float bv = c0v; int bi = c0i; float bz = c0z;
      if (c1v > bv || (c1v == bv && c1i < bi)) { bv = c1v; bi = c1i; bz = c1z; }
#pragma unroll
      for (int off = 1; off < 64; off <<= 1) {
        float ov = __shfl_xor(bv, off);
        int oi = __shfl_xor(bi, off);
        float oz = __shfl_xor(bz, off);
        if (ov > bv || (ov == bv && oi < bi)) { bv = ov; bi = oi; bz = oz; }
      }
      if (bv <= 0.0f) break;              // remaining zsel stay 0 (== reference)
      if (lane == 0) s_zsel[kk] = bz;     // same-wave LDS RAW: in-order, no barrier
      if (c0i == bi) c0v = -1.0f;         // idx unique: exactly the winner clears
      if (c1i == bi) c1v = -1.0f;
    }
  }

  // ---------------- Phase D/E: gaussian slots, sort, fill, sort (wave 0) -----
  if (wid == 0) {
    float sortv;
    if (lane < N_S - N_G) {
      sortv = s_zsel[lane];
    } else if (lane < N_S) {
      const float g = gn[(size_t)ray * N_G + (lane - (N_S - N_G))];
      sortv = raymask ? (g * stdz + meanz) : 0.0f;
    } else {
      sortv = INFINITY;
    }
    float z = bitonic64(sortv, lane);
    const bool miss = (lane < N_S) && (z == 0.0f);
    const int nmiss_raw = __popcll(__ballot(miss));
    const int nmiss = (nmiss_raw < 1) ? 1 : nmiss_raw;
    const float stepf = __fdiv_rn(__fsub_rn(farv, nearv), (float)nmiss);
    if (miss) {
      const float ufv = uf[(size_t)ray * N_S + lane];
      z = __fadd_rn(__fadd_rn(nearv, __fmul_rn((float)lane, stepf)), __fmul_rn(ufv, stepf));
    }
    z = bitonic64(z, lane);
    const float zn = __shfl_down(z, 1);
    const float delta = (lane == N_S - 1) ? (farv - z) : (zn - z);
    if (lane < N_S) { s_zarr[lane] = z; s_darr[lane] = delta; }
  }
  __syncthreads();                                    // #6

  // ---------------- Phase F1: MLP, 10 samples/wave, multi-channel reduce -----
  {
    const float b2r = (lane < 4) ? b2[lane] : 0.0f;
    float w1r[24], b1r[4], w2r[16];
#pragma unroll
    for (int m = 0; m < 4; ++m) {
      const int j = lane + 64 * m;
#pragma unroll
      for (int k = 0; k < 6; ++k) w1r[k * 4 + m] = W1[k * N_HID + j];
      b1r[m] = b1[j];
      const float4 w2v = *(const float4*)(W2 + (size_t)j * 4);
      w2r[m * 4 + 0] = w2v.x; w2r[m * 4 + 1] = w2v.y;
      w2r[m * 4 + 2] = w2v.z; w2r[m * 4 + 3] = w2v.w;
    }
#pragma unroll 1
    for (int q = 0; q < 10; ++q) {
      const int s = wid * 10 + q;
      const float zq = s_zarr[s];
      const float px = ox + zq * dx;
      const float py = oy + zq * dy;
      const float pz = oz + zq * dz;
      float a0 = 0.0f, a1 = 0.0f, a2 = 0.0f, a3 = 0.0f;
#pragma unroll
      for (int m = 0; m < 4; ++m) {
        float h = b1r[m];
        h = fmaf(px, w1r[0 * 4 + m], h);
        h = fmaf(py, w1r[1 * 4 + m], h);
        h = fmaf(pz, w1r[2 * 4 + m], h);
        h = fmaf(dx, w1r[3 * 4 + m], h);
        h = fmaf(dy, w1r[4 * 4 + m], h);
        h = fmaf(dz, w1r[5 * 4 + m], h);
        h = fmaxf(h, 0.0f);
        a0 = fmaf(h, w2r[m * 4 + 0], a0);
        a1 = fmaf(h, w2r[m * 4 + 1], a1);
        a2 = fmaf(h, w2r[m * 4 + 2], a2);
        a3 = fmaf(h, w2r[m * 4 + 3], a3);
      }
      // multi-channel butterfly: lane (l&3) ends with channel (l&3) total
      const float s0 = __shfl_xor(a0, 1), s1 = __shfl_xor(a1, 1);
      const float s2 = __shfl_xor(a2, 1), s3 = __shfl_xor(a3, 1);
      const float m0 = (lane & 1) ? (a1 + s1) : (a0 + s0);
      const float m1 = (lane & 1) ? (a3 + s3) : (a2 + s2);
      const float t0 = __shfl_xor(m0, 2), t1 = __shfl_xor(m1, 2);
      float r = (lane & 2) ? (m1 + t1) : (m0 + t0);
#pragma unroll
      for (int off = 4; off < 64; off <<= 1) r += __shfl_xor(r, off);
      if (lane < 4) s_mlp[s * 4 + lane] = r + b2r;
    }
  }
  __syncthreads();                                    // #7

  // ---------------- Phase F2: composite + output (wave 0) --------------------
  if (wid == 0) {
    float alpha = 0.0f, r0 = 0.0f, r1 = 0.0f, r2 = 0.0f, zl = 0.0f;
    float factor = 1.0f;
    if (lane < N_S) {
      zl = s_zarr[lane];
      const float dl = s_darr[lane];
      r0 = s_mlp[lane * 4 + 0];
      r1 = s_mlp[lane * 4 + 1];
      r2 = s_mlp[lane * 4 + 2];
      const float rsig = fmaxf(s_mlp[lane * 4 + 3], 0.0f);
      alpha = 1.0f - expf(-dl * rsig);
      factor = (1.0f - alpha) + 1e-10f;
    }
    float incp = factor;
#pragma unroll
    for (int off = 1; off < 64; off <<= 1) {
      float o = __shfl_up(incp, off);
      if (lane >= off) incp *= o;
    }
    float T = __shfl_up(incp, 1);
    if (lane == 0) T = 1.0f;

    const float w = (lane < N_S) ? alpha * T : 0.0f;
    const float wz = (lane < N_S) ? w * zl : 0.0f;
    const float wr0 = (lane < N_S) ? w * r0 : 0.0f;
    const float wr1 = (lane < N_S) ? w * r1 : 0.0f;
    const float wr2 = (lane < N_S) ? w * r2 : 0.0f;

    const float wsum = wave_sum(w);
    const float dsum = wave_sum(wz);
    const float c0s = wave_sum(wr0);
    const float c1s = wave_sum(wr1);
    const float c2s = wave_sum(wr2);

    if (lane < N_S) out[(size_t)ray * N_S + lane] = w;
    if (lane == 0) {
      float* rgbo = out + (size_t)N_SB * N_R * N_S + (size_t)ray * 3;
      rgbo[0] = (c0s + 1.0f) - wsum;
      rgbo[1] = (c1s + 1.0f) - wsum;
      rgbo[2] = (c2s + 1.0f) - wsum;
      out[(size_t)N_SB * N_R * N_S + (size_t)N_SB * N_R * 3 + ray] = dsum;
    }
  }
}

extern "C" void kernel_launch(void* const* d_in, const int* in_sizes, int n_in,
                              void* d_out, int out_size, void* d_ws, size_t ws_size,
                              hipStream_t stream) {
  const float* rays  = (const float*)d_in[0];
  const float* poses = (const float*)d_in[1];
  const float* focal = (const float*)d_in[2];
  const float* cvec  = (const float*)d_in[3];
  const float* dmap  = (const float*)d_in[4];
  const float* smap  = (const float*)d_in[5];
  const float* nmap  = (const float*)d_in[6];
  const float* W1p   = (const float*)d_in[7];
  const float* b1p   = (const float*)d_in[8];
  const float* W2p   = (const float*)d_in[9];
  const float* b2p   = (const float*)d_in[10];
  const float* ucp   = (const float*)d_in[11];
  const float* gnp   = (const float*)d_in[12];
  const float* ufp   = (const float*)d_in[13];
  float* outp = (float*)d_out;

  dim3 grid(N_SB * N_R);   // one ray per block
  dim3 block(256);
  nerf_all<<<grid, block, 0, stream>>>(rays, poses, focal, cvec, dmap, smap, nmap,
                                       W1p, b1p, W2p, b2p, ucp, gnp, ufp, outp);
}

// Round 5
// 113.287 us; speedup vs baseline: 1.9394x; 1.3730x over previous
//
#include <hip/hip_runtime.h>
#include <math.h>

#define N_SB 2
#define N_V  3
#define N_R  2048
#define N_C  1000
#define N_S  40
#define N_G  15
#define N_HID 256
#define HW 65536
#define CAP 256   // compacted candidate list capacity (expected ~90, max ~125)

__device__ __forceinline__ float wave_sum(float v) {
#pragma unroll
  for (int off = 32; off > 0; off >>= 1) v += __shfl_xor(v, off);
  return v;
}

// XLA/Eigen f32 erf: rational poly in x^2, clamp to +-erfinv(1-2^-23).
// Must stay bit-identical across rounds (pt feeds discrete top-k selection).
__device__ __forceinline__ float erf_xla(float x) {
  const float c = 3.832506856900711f;
  x = fminf(fmaxf(x, -c), c);
  float x2 = __fmul_rn(x, x);
  float p = 0.00022905065861350646f;
  p = __fadd_rn(__fmul_rn(p, x2), 0.0034082910107109506f);
  p = __fadd_rn(__fmul_rn(p, x2), 0.050955695062380861f);
  p = __fadd_rn(__fmul_rn(p, x2), 0.18520832239976145f);
  p = __fadd_rn(__fmul_rn(p, x2), 1.128379143519084f);
  float q = -1.1791602954361697e-7f;
  q = __fadd_rn(__fmul_rn(q, x2), 0.000023547966471313185f);
  q = __fadd_rn(__fmul_rn(q, x2), 0.0010179625278914885f);
  q = __fadd_rn(__fmul_rn(q, x2), 0.014070470171167667f);
  q = __fadd_rn(__fmul_rn(q, x2), 0.11098505178285362f);
  q = __fadd_rn(__fmul_rn(q, x2), 0.49746925110067538f);
  q = __fadd_rn(__fmul_rn(q, x2), 1.0f);
  return __fdiv_rn(__fmul_rn(x, p), q);
}

__device__ __forceinline__ float bitonic64(float v, int lane) {
#pragma unroll
  for (int k = 2; k <= 64; k <<= 1) {
#pragma unroll
    for (int j = k >> 1; j >= 1; j >>= 1) {
      float o = __shfl_xor(v, j);
      bool up = ((lane & k) == 0);
      bool lower = ((lane & j) == 0);
      v = (lower == up) ? fminf(v, o) : fmaxf(v, o);
    }
  }
  return v;
}

__global__ __launch_bounds__(256, 8)   // 8 blocks/CU: 32 waves/CU latency pool
void nerf_all(const float* __restrict__ rays, const float* __restrict__ poses,
              const float* __restrict__ focal, const float* __restrict__ cvec,
              const float* __restrict__ dmap, const float* __restrict__ smap,
              const float* __restrict__ nmap, const float* __restrict__ W1,
              const float* __restrict__ b1, const float* __restrict__ W2,
              const float* __restrict__ b2, const float* __restrict__ uc,
              const float* __restrict__ gn, const float* __restrict__ uf,
              float* __restrict__ out)
{
  __shared__ __align__(16) float s_pt[1024];
  __shared__ __align__(16) float s_zc[1024];
  __shared__ float s_lv[CAP];
  __shared__ int   s_li[CAP];
  __shared__ float s_lz[CAP];
  __shared__ int   s_cnt;
  __shared__ float s_cv[100];
  __shared__ int   s_ci[100];
  __shared__ float s_cz[100];
  __shared__ float s_zsel[32];
  __shared__ float s_wtot[4], s_sO[4], s_sZ[4], s_sV[4];
  __shared__ int   s_fl[4];
  __shared__ float s_zarr[N_S], s_darr[N_S];
  __shared__ float s_mlp[N_S * 4];

  const int tid = threadIdx.x;
  const int wid = tid >> 6;
  const int lane = tid & 63;
  const int ray = blockIdx.x;       // one ray per block
  const int sb = ray >> 11;

  // init (ordered vs later use by barrier #1)
  if (tid == 0) s_cnt = 0;
  if (tid < 100) { s_cv[tid] = 0.0f; s_ci[tid] = 0x40000000; s_cz[tid] = 0.0f; }
  if (tid < 32) s_zsel[tid] = 0.0f;

  const float* rp = rays + (size_t)ray * 8;   // uniform per block -> SGPRs
  const float ox = rp[0], oy = rp[1], oz = rp[2];
  const float dx = rp[3], dy = rp[4], dz = rp[5];
  const float nearv = rp[6], farv = rp[7];

  const float lindelta = 0.999f / 999.0f;
  const float ssv = __fdiv_rn(__fsub_rn(farv, nearv), 1000.0f);
  const float sshalf = __fmul_rn(ssv, 0.5f);
  const float SQRT2 = 1.41421356237309515f;

  // ---------------- Phase A: lane-adjacent samples, depth-gated gathers ------
  float zg[4] = {0.0f, 0.0f, 0.0f, 0.0f};
  float ptg[4] = {0.0f, 0.0f, 0.0f, 0.0f};
#pragma unroll
  for (int cch = 0; cch < 4; ++cch) {
    const int i = cch * 256 + tid;
    if (i < N_C) {
      const float u = uc[(size_t)ray * N_C + i];
      const float zs = __fadd_rn(__fmul_rn((float)i, lindelta), __fmul_rn(u, 0.001f));
      const float zc = __fadd_rn(__fmul_rn(nearv, __fsub_rn(1.0f, zs)), __fmul_rn(farv, zs));
      zg[cch] = zc;
      s_zc[i] = zc;
    }
  }

#pragma unroll 1
  for (int v = 0; v < N_V; ++v) {
    const float* pp = poses + (size_t)(sb * N_V + v) * 16;
    const float R00 = pp[0], R01 = pp[1], R02 = pp[2], t0 = pp[3];
    const float R10 = pp[4], R11 = pp[5], R12 = pp[6], t1 = pp[7];
    const float R20 = pp[8], R21 = pp[9], R22 = pp[10], t2 = pp[11];
    const float fx = focal[(sb * N_V + v) * 2 + 0];
    const float fy = focal[(sb * N_V + v) * 2 + 1];
    const float cx = cvec[(sb * N_V + v) * 2 + 0];
    const float cy = cvec[(sb * N_V + v) * 2 + 1];
    const float rdx = __fadd_rn(__fadd_rn(__fmul_rn(R00, dx), __fmul_rn(R01, dy)), __fmul_rn(R02, dz));
    const float rdy = __fadd_rn(__fadd_rn(__fmul_rn(R10, dx), __fmul_rn(R11, dy)), __fmul_rn(R12, dz));
    const float rdz = __fadd_rn(__fadd_rn(__fmul_rn(R20, dx), __fmul_rn(R21, dy)), __fmul_rn(R22, dz));
    const float* dmv = dmap + (size_t)(sb * N_V + v) * HW;
    const float* smv = smap + (size_t)(sb * N_V + v) * HW;
    const float* nmv = nmap + (size_t)(sb * N_V + v) * 3 * HW;

    // stage 1: project all 4 chunks, issue all 4 rd loads (pipelined).
    int   linv[4];
    float Zcv[4];
    float rdv[4];
#pragma unroll
    for (int cch = 0; cch < 4; ++cch) {
      const float zc = zg[cch];
      const float xw = __fadd_rn(ox, __fmul_rn(zc, dx));
      const float yw = __fadd_rn(oy, __fmul_rn(zc, dy));
      const float zw = __fadd_rn(oz, __fmul_rn(zc, dz));
      const float Xc = __fadd_rn(__fadd_rn(__fadd_rn(__fmul_rn(R00, xw), __fmul_rn(R01, yw)), __fmul_rn(R02, zw)), t0);
      const float Yc = __fadd_rn(__fadd_rn(__fadd_rn(__fmul_rn(R10, xw), __fmul_rn(R11, yw)), __fmul_rn(R12, zw)), t1);
      const float Zc = __fadd_rn(__fadd_rn(__fadd_rn(__fmul_rn(R20, xw), __fmul_rn(R21, yw)), __fmul_rn(R22, zw)), t2);
      const float iu = __fdiv_rn(Xc, Zc);
      const float iv = __fdiv_rn(Yc, Zc);
      const float su = __fadd_rn(__fmul_rn(iu, fx), cx);
      const float sv = __fadd_rn(__fmul_rn(iv, fy), cy);
      const float unorm = __fsub_rn(__fmul_rn(__fmul_rn(su, 1.0f / 256.0f), 2.0f), 1.0f);
      const float vnorm = __fsub_rn(__fmul_rn(__fmul_rn(sv, 1.0f / 256.0f), 2.0f), 1.0f);
      const float xf = __fsub_rn(__fmul_rn(__fmul_rn(__fadd_rn(unorm, 1.0f), 0.5f), 256.0f), 0.5f);
      const float yf = __fsub_rn(__fmul_rn(__fmul_rn(__fadd_rn(vnorm, 1.0f), 0.5f), 256.0f), 0.5f);
      const int px = (int)fminf(fmaxf(rintf(xf), 0.0f), 255.0f);
      const int py = (int)fminf(fmaxf(rintf(yf), 0.0f), 255.0f);
      linv[cch] = py * 256 + px;
      Zcv[cch] = Zc;
      rdv[cch] = dmv[linv[cch]];
    }

    // stage 2: depth-gate (~3% pass) -> remaining gathers + erf only then.
#pragma unroll
    for (int cch = 0; cch < 4; ++cch) {
      const int i = cch * 256 + tid;
      const float Zc = Zcv[cch];
      const float rd = rdv[cch];
      if (i < N_C && fabsf(__fsub_rn(rd, Zc)) < 0.05f) {
        const int lin = linv[cch];
        const float rs = smv[lin];
        const float n0 = nmv[lin];
        const float n1 = nmv[HW + lin];
        const float n2 = nmv[2 * HW + lin];
        const float cosd = __fadd_rn(__fadd_rn(__fmul_rn(rdx, n0), __fmul_rn(rdy, n1)), __fmul_rn(rdz, n2));
        if ((rs != 0.0f) && (cosd <= 0.0f)) {
          const float invv = __fdiv_rn(1.0f, __fmul_rn(rs, SQRT2));
          const float a1 = __fmul_rn(__fsub_rn(__fadd_rn(Zc, sshalf), rd), invv);
          const float a2 = __fmul_rn(__fsub_rn(__fsub_rn(Zc, sshalf), rd), invv);
          const float ptv = __fmul_rn(0.5f, fabsf(__fsub_rn(erf_xla(a1), erf_xla(a2))));
          ptg[cch] = fmaxf(ptg[cch], ptv);
        }
      }
    }
  }
#pragma unroll
  for (int cch = 0; cch < 4; ++cch) {
    const int i = cch * 256 + tid;
    if (i < N_C) s_pt[i] = ptg[cch];
  }
  __syncthreads();                                    // #1

  // ---------------- ownership switch: thread owns 4 consecutive samples ------
  const bool act = (tid < 250);
  float ptm[4] = {0.0f, 0.0f, 0.0f, 0.0f};
  float zcr[4] = {0.0f, 0.0f, 0.0f, 0.0f};
  if (act) {
    const float4 p4 = *(const float4*)&s_pt[tid * 4];
    ptm[0] = p4.x; ptm[1] = p4.y; ptm[2] = p4.z; ptm[3] = p4.w;
    const float4 z4 = *(const float4*)&s_zc[tid * 4];
    zcr[0] = z4.x; zcr[1] = z4.y; zcr[2] = z4.z; zcr[3] = z4.w;
  }

  // ---------------- Phase B: block scan + moments ----------------------------
  float lp = 1.0f;
  if (act) {
#pragma unroll
    for (int k = 0; k < 4; ++k) lp = __fmul_rn(lp, __fsub_rn(1.0f, ptm[k]));
  }
  float inc = lp;
#pragma unroll
  for (int off = 1; off < 64; off <<= 1) {
    float o = __shfl_up(inc, off);
    if (lane >= off) inc *= o;
  }
  if (lane == 63) s_wtot[wid] = inc;
  __syncthreads();                                    // #2
  float pw = 1.0f;
  if (wid > 0) pw *= s_wtot[0];
  if (wid > 1) pw *= s_wtot[1];
  if (wid > 2) pw *= s_wtot[2];
  float exc = __shfl_up(inc, 1);
  if (lane == 0) exc = 1.0f;
  exc *= pw;

  float accO = 0.0f, accZO = 0.0f;
  bool anynz = false;
  if (act) {
    float run = exc;
#pragma unroll
    for (int k = 0; k < 4; ++k) {
      float o = ptm[k] * run;
      accO += o;
      accZO += zcr[k] * o;
      anynz |= (o != 0.0f);
      run *= (1.0f - ptm[k]);
    }
  }
  accO = wave_sum(accO);
  accZO = wave_sum(accZO);
  const int anyw = __any(anynz) ? 1 : 0;
  if (lane == 0) { s_sO[wid] = accO; s_sZ[wid] = accZO; s_fl[wid] = anyw; }
  __syncthreads();                                    // #3
  const float tO = s_sO[0] + s_sO[1] + s_sO[2] + s_sO[3];
  const float tZ = s_sZ[0] + s_sZ[1] + s_sZ[2] + s_sZ[3];
  const bool raymask = (s_fl[0] | s_fl[1] | s_fl[2] | s_fl[3]) != 0;
  const float swd = (tO > 0.0f) ? tO : 1.0f;
  const float meanz = __fdiv_rn(tZ, swd);

  float accV = 0.0f;
  if (act) {
    float run = exc;
#pragma unroll
    for (int k = 0; k < 4; ++k) {
      float o = ptm[k] * run;
      float d = zcr[k] - meanz;
      accV += o * d * d;
      run *= (1.0f - ptm[k]);
    }
  }
  accV = wave_sum(accV);
  if (lane == 0) s_sV[wid] = accV;
  __syncthreads();                                    // #4
  const float tV = s_sV[0] + s_sV[1] + s_sV[2] + s_sV[3];
  const float stdz = sqrtf(__fdiv_rn(tV, swd));

  // ---------------- Phase C0: compact nonzero candidates into LDS list -------
  // List order is nondeterministic (atomicAdd) but selection compares
  // (val desc, idx asc) exactly, so the OUTPUT is deterministic.
  {
    float lv[4]; int li[4]; float lz[4];
    int nloc = 0;
    if (act) {
#pragma unroll
      for (int k = 0; k < 4; ++k) {
        if (ptm[k] > 0.0f) { lv[nloc] = ptm[k]; li[nloc] = tid * 4 + k; lz[nloc] = zcr[k]; ++nloc; }
      }
    }
    int base = 0;
    if (nloc > 0) base = atomicAdd(&s_cnt, nloc);
    if (base + nloc <= CAP) {
      for (int j = 0; j < nloc; ++j) {
        s_lv[base + j] = lv[j];
        s_li[base + j] = li[j];
        s_lz[base + j] = lz[j];
      }
    }
  }
  __syncthreads();                                    // #5
  const int cnt = s_cnt;   // block-uniform

  if (cnt <= CAP) {
    // -------------- Phase C-fast: wave-0 top-25 over compacted list ----------
    if (wid == 0) {
      float rv[4]; int ri[4]; float rz[4];
#pragma unroll
      for (int j = 0; j < 4; ++j) {
        const int p = lane + j * 64;
        if (p < cnt) { rv[j] = s_lv[p]; ri[j] = s_li[p]; rz[j] = s_lz[p]; }
        else         { rv[j] = -2.0f; ri[j] = 0x40000000; rz[j] = 0.0f; }
      }
#pragma unroll 1
      for (int kk = 0; kk < 25; ++kk) {
        float bv = -2.0f; int bi = 0x40000000;
#pragma unroll
        for (int j = 0; j < 4; ++j) {
          if (rv[j] > bv || (rv[j] == bv && ri[j] < bi)) { bv = rv[j]; bi = ri[j]; }
        }
#pragma unroll
        for (int off = 1; off < 64; off <<= 1) {
          const float ov = __shfl_xor(bv, off);
          const int oi = __shfl_xor(bi, off);
          if (ov > bv || (ov == bv && oi < bi)) { bv = ov; bi = oi; }
        }
        if (bv <= 0.0f) break;   // rest of zsel stay 0 (== reference)
#pragma unroll
        for (int j = 0; j < 4; ++j) {
          if (ri[j] == bi) {      // unique global idx: exactly one lane fires
            s_zsel[kk] = rz[j];   // same-wave LDS RAW: in-order
            rv[j] = -1.0f;
          }
        }
      }
    }
  } else {
    // -------------- Phase C-fallback (exact, any data): old C1 + C2 ----------
    const int cbase = wid * 25;
#pragma unroll 1
    for (int kk = 0; kk < 25; ++kk) {
      float bv = -2.0f;
      int bi = 0x40000000;
      if (act) {
#pragma unroll
        for (int k = 0; k < 4; ++k) {
          if (ptm[k] > bv) { bv = ptm[k]; bi = tid * 4 + k; }
        }
      }
#pragma unroll
      for (int off = 1; off < 64; off <<= 1) {
        float ov = __shfl_xor(bv, off);
        int oi = __shfl_xor(bi, off);
        if (ov > bv || (ov == bv && oi < bi)) { bv = ov; bi = oi; }
      }
      if (bv <= 0.0f) break;
      if (tid == (bi >> 2)) {
        s_cv[cbase + kk] = bv;
        s_ci[cbase + kk] = bi;
        const int r = bi & 3;
        float zk;
        if (r == 0)      { zk = zcr[0]; ptm[0] = -1.0f; }
        else if (r == 1) { zk = zcr[1]; ptm[1] = -1.0f; }
        else if (r == 2) { zk = zcr[2]; ptm[2] = -1.0f; }
        else             { zk = zcr[3]; ptm[3] = -1.0f; }
        s_cz[cbase + kk] = zk;
      }
    }
    __syncthreads();
    if (wid == 0) {
      float c0v = s_cv[lane];
      int   c0i = s_ci[lane];
      float c0z = s_cz[lane];
      float c1v = -2.0f; int c1i = 0x40000000; float c1z = 0.0f;
      if (lane + 64 < 100) { c1v = s_cv[lane + 64]; c1i = s_ci[lane + 64]; c1z = s_cz[lane + 64]; }
#pragma unroll 1
      for (int kk = 0; kk < 25; ++kk) {
        float bv = c0v; int bi = c0i; float bz = c0z;
        if (c1v > bv || (c1v == bv && c1i < bi)) { bv = c1v; bi = c1i; bz = c1z; }
#pragma unroll
        for (int off = 1; off < 64; off <<= 1) {
          float ov = __shfl_xor(bv, off);
          int oi = __shfl_xor(bi, off);
          float oz = __shfl_xor(bz, off);
          if (ov > bv || (ov == bv && oi < bi)) { bv = ov; bi = oi; bz = oz; }
        }
        if (bv <= 0.0f) break;
        if (lane == 0) s_zsel[kk] = bz;
        if (c0i == bi) c0v = -1.0f;
        if (c1i == bi) c1v = -1.0f;
      }
    }
  }

  // ---------------- Phase D/E: gaussian slots, sort, fill, sort (wave 0) -----
  if (wid == 0) {
    float sortv;
    if (lane < N_S - N_G) {
      sortv = s_zsel[lane];
    } else if (lane < N_S) {
      const float g = gn[(size_t)ray * N_G + (lane - (N_S - N_G))];
      sortv = raymask ? (g * stdz + meanz) : 0.0f;
    } else {
      sortv = INFINITY;
    }
    float z = bitonic64(sortv, lane);
    const bool miss = (lane < N_S) && (z == 0.0f);
    const int nmiss_raw = __popcll(__ballot(miss));
    const int nmiss = (nmiss_raw < 1) ? 1 : nmiss_raw;
    const float stepf = __fdiv_rn(__fsub_rn(farv, nearv), (float)nmiss);
    if (miss) {
      const float ufv = uf[(size_t)ray * N_S + lane];
      z = __fadd_rn(__fadd_rn(nearv, __fmul_rn((float)lane, stepf)), __fmul_rn(ufv, stepf));
    }
    z = bitonic64(z, lane);
    const float zn = __shfl_down(z, 1);
    const float delta = (lane == N_S - 1) ? (farv - z) : (zn - z);
    if (lane < N_S) { s_zarr[lane] = z; s_darr[lane] = delta; }
  }
  __syncthreads();                                    // #6

  // ---------------- Phase F1: MLP, 10 samples/wave, multi-channel reduce -----
  {
    const float b2r = (lane < 4) ? b2[lane] : 0.0f;
    float w1r[24], b1r[4], w2r[16];
#pragma unroll
    for (int m = 0; m < 4; ++m) {
      const int j = lane + 64 * m;
#pragma unroll
      for (int k = 0; k < 6; ++k) w1r[k * 4 + m] = W1[k * N_HID + j];
      b1r[m] = b1[j];
      const float4 w2v = *(const float4*)(W2 + (size_t)j * 4);
      w2r[m * 4 + 0] = w2v.x; w2r[m * 4 + 1] = w2v.y;
      w2r[m * 4 + 2] = w2v.z; w2r[m * 4 + 3] = w2v.w;
    }
#pragma unroll 1
    for (int q = 0; q < 10; ++q) {
      const int s = wid * 10 + q;
      const float zq = s_zarr[s];
      const float px = ox + zq * dx;
      const float py = oy + zq * dy;
      const float pz = oz + zq * dz;
      float a0 = 0.0f, a1 = 0.0f, a2 = 0.0f, a3 = 0.0f;
#pragma unroll
      for (int m = 0; m < 4; ++m) {
        float h = b1r[m];
        h = fmaf(px, w1r[0 * 4 + m], h);
        h = fmaf(py, w1r[1 * 4 + m], h);
        h = fmaf(pz, w1r[2 * 4 + m], h);
        h = fmaf(dx, w1r[3 * 4 + m], h);
        h = fmaf(dy, w1r[4 * 4 + m], h);
        h = fmaf(dz, w1r[5 * 4 + m], h);
        h = fmaxf(h, 0.0f);
        a0 = fmaf(h, w2r[m * 4 + 0], a0);
        a1 = fmaf(h, w2r[m * 4 + 1], a1);
        a2 = fmaf(h, w2r[m * 4 + 2], a2);
        a3 = fmaf(h, w2r[m * 4 + 3], a3);
      }
      // multi-channel butterfly: lane (l&3) ends with channel (l&3) total
      const float s0 = __shfl_xor(a0, 1), s1 = __shfl_xor(a1, 1);
      const float s2 = __shfl_xor(a2, 1), s3 = __shfl_xor(a3, 1);
      const float m0 = (lane & 1) ? (a1 + s1) : (a0 + s0);
      const float m1 = (lane & 1) ? (a3 + s3) : (a2 + s2);
      const float t0 = __shfl_xor(m0, 2), t1 = __shfl_xor(m1, 2);
      float r = (lane & 2) ? (m1 + t1) : (m0 + t0);
#pragma unroll
      for (int off = 4; off < 64; off <<= 1) r += __shfl_xor(r, off);
      if (lane < 4) s_mlp[s * 4 + lane] = r + b2r;
    }
  }
  __syncthreads();                                    // #7

  // ---------------- Phase F2: composite + output (wave 0) --------------------
  if (wid == 0) {
    float alpha = 0.0f, r0 = 0.0f, r1 = 0.0f, r2 = 0.0f, zl = 0.0f;
    float factor = 1.0f;
    if (lane < N_S) {
      zl = s_zarr[lane];
      const float dl = s_darr[lane];
      r0 = s_mlp[lane * 4 + 0];
      r1 = s_mlp[lane * 4 + 1];
      r2 = s_mlp[lane * 4 + 2];
      const float rsig = fmaxf(s_mlp[lane * 4 + 3], 0.0f);
      alpha = 1.0f - expf(-dl * rsig);
      factor = (1.0f - alpha) + 1e-10f;
    }
    float incp = factor;
#pragma unroll
    for (int off = 1; off < 64; off <<= 1) {
      float o = __shfl_up(incp, off);
      if (lane >= off) incp *= o;
    }
    float T = __shfl_up(incp, 1);
    if (lane == 0) T = 1.0f;

    const float w = (lane < N_S) ? alpha * T : 0.0f;
    const float wz = (lane < N_S) ? w * zl : 0.0f;
    const float wr0 = (lane < N_S) ? w * r0 : 0.0f;
    const float wr1 = (lane < N_S) ? w * r1 : 0.0f;
    const float wr2 = (lane < N_S) ? w * r2 : 0.0f;

    const float wsum = wave_sum(w);
    const float dsum = wave_sum(wz);
    const float c0s = wave_sum(wr0);
    const float c1s = wave_sum(wr1);
    const float c2s = wave_sum(wr2);

    if (lane < N_S) out[(size_t)ray * N_S + lane] = w;
    if (lane == 0) {
      float* rgbo = out + (size_t)N_SB * N_R * N_S + (size_t)ray * 3;
      rgbo[0] = (c0s + 1.0f) - wsum;
      rgbo[1] = (c1s + 1.0f) - wsum;
      rgbo[2] = (c2s + 1.0f) - wsum;
      out[(size_t)N_SB * N_R * N_S + (size_t)N_SB * N_R * 3 + ray] = dsum;
    }
  }
}

extern "C" void kernel_launch(void* const* d_in, const int* in_sizes, int n_in,
                              void* d_out, int out_size, void* d_ws, size_t ws_size,
                              hipStream_t stream) {
  const float* rays  = (const float*)d_in[0];
  const float* poses = (const float*)d_in[1];
  const float* focal = (const float*)d_in[2];
  const float* cvec  = (const float*)d_in[3];
  const float* dmap  = (const float*)d_in[4];
  const float* smap  = (const float*)d_in[5];
  const float* nmap  = (const float*)d_in[6];
  const float* W1p   = (const float*)d_in[7];
  const float* b1p   = (const float*)d_in[8];
  const float* W2p   = (const float*)d_in[9];
  const float* b2p   = (const float*)d_in[10];
  const float* ucp   = (const float*)d_in[11];
  const float* gnp   = (const float*)d_in[12];
  const float* ufp   = (const float*)d_in[13];
  float* outp = (float*)d_out;

  dim3 grid(N_SB * N_R);   // one ray per block
  dim3 block(256);
  nerf_all<<<grid, block, 0, stream>>>(rays, poses, focal, cvec, dmap, smap, nmap,
                                       W1p, b1p, W2p, b2p, ucp, gnp, ufp, outp);
}

// Round 6
// 96.586 us; speedup vs baseline: 2.2748x; 1.1729x over previous
//
#include <hip/hip_runtime.h>
#include <math.h>

#define N_SB 2
#define N_V  3
#define N_R  2048
#define N_C  1000
#define N_S  40
#define N_G  15
#define N_HID 256
#define HW 65536
#define CAP 256   // compacted candidate list capacity (expected ~90, max ~125)

__device__ __forceinline__ float wave_sum(float v) {
#pragma unroll
  for (int off = 32; off > 0; off >>= 1) v += __shfl_xor(v, off);
  return v;
}

// XLA/Eigen f32 erf: rational poly in x^2, clamp to +-erfinv(1-2^-23).
// Must stay bit-identical across rounds (pt feeds discrete top-k selection).
__device__ __forceinline__ float erf_xla(float x) {
  const float c = 3.832506856900711f;
  x = fminf(fmaxf(x, -c), c);
  float x2 = __fmul_rn(x, x);
  float p = 0.00022905065861350646f;
  p = __fadd_rn(__fmul_rn(p, x2), 0.0034082910107109506f);
  p = __fadd_rn(__fmul_rn(p, x2), 0.050955695062380861f);
  p = __fadd_rn(__fmul_rn(p, x2), 0.18520832239976145f);
  p = __fadd_rn(__fmul_rn(p, x2), 1.128379143519084f);
  float q = -1.1791602954361697e-7f;
  q = __fadd_rn(__fmul_rn(q, x2), 0.000023547966471313185f);
  q = __fadd_rn(__fmul_rn(q, x2), 0.0010179625278914885f);
  q = __fadd_rn(__fmul_rn(q, x2), 0.014070470171167667f);
  q = __fadd_rn(__fmul_rn(q, x2), 0.11098505178285362f);
  q = __fadd_rn(__fmul_rn(q, x2), 0.49746925110067538f);
  q = __fadd_rn(__fmul_rn(q, x2), 1.0f);
  return __fdiv_rn(__fmul_rn(x, p), q);
}

__device__ __forceinline__ float bitonic64(float v, int lane) {
#pragma unroll
  for (int k = 2; k <= 64; k <<= 1) {
#pragma unroll
    for (int j = k >> 1; j >= 1; j >>= 1) {
      float o = __shfl_xor(v, j);
      bool up = ((lane & k) == 0);
      bool lower = ((lane & j) == 0);
      v = (lower == up) ? fminf(v, o) : fmaxf(v, o);
    }
  }
  return v;
}

__global__ __launch_bounds__(256, 8)   // 8 blocks/CU: 32 waves/CU latency pool
void nerf_all(const float* __restrict__ rays, const float* __restrict__ poses,
              const float* __restrict__ focal, const float* __restrict__ cvec,
              const float* __restrict__ dmap, const float* __restrict__ smap,
              const float* __restrict__ nmap, const float* __restrict__ W1,
              const float* __restrict__ b1, const float* __restrict__ W2,
              const float* __restrict__ b2, const float* __restrict__ uc,
              const float* __restrict__ gn, const float* __restrict__ uf,
              float* __restrict__ out)
{
  __shared__ __align__(16) float s_pt[1024];
  __shared__ __align__(16) float s_zc[1024];
  __shared__ float s_lv[CAP];
  __shared__ int   s_li[CAP];
  __shared__ float s_lz[CAP];
  __shared__ int   s_cnt;
  __shared__ float s_cv[100];
  __shared__ int   s_ci[100];
  __shared__ float s_cz[100];
  __shared__ float s_zsel[32];
  __shared__ float s_wtot[4], s_sO[4], s_sZ[4], s_sV[4];
  __shared__ int   s_fl[4];
  __shared__ float s_zarr[N_S], s_darr[N_S];
  __shared__ float s_mlp[N_S * 4];

  const int tid = threadIdx.x;
  const int wid = tid >> 6;
  const int lane = tid & 63;
  const int ray = blockIdx.x;       // one ray per block
  const int sb = ray >> 11;

  // init (ordered vs later use by barrier #1)
  if (tid == 0) s_cnt = 0;
  if (tid < 100) { s_cv[tid] = 0.0f; s_ci[tid] = 0x40000000; s_cz[tid] = 0.0f; }
  if (tid < 32) s_zsel[tid] = 0.0f;

  const float* rp = rays + (size_t)ray * 8;   // uniform per block -> SGPRs
  const float ox = rp[0], oy = rp[1], oz = rp[2];
  const float dx = rp[3], dy = rp[4], dz = rp[5];
  const float nearv = rp[6], farv = rp[7];

  const float lindelta = 0.999f / 999.0f;
  const float ssv = __fdiv_rn(__fsub_rn(farv, nearv), 1000.0f);
  const float sshalf = __fmul_rn(ssv, 0.5f);
  const float SQRT2 = 1.41421356237309515f;

  // ---------------- Phase A: lane-adjacent samples, depth-gated gathers ------
  float zg[4] = {0.0f, 0.0f, 0.0f, 0.0f};
  float ptg[4] = {0.0f, 0.0f, 0.0f, 0.0f};
#pragma unroll
  for (int cch = 0; cch < 4; ++cch) {
    const int i = cch * 256 + tid;
    if (i < N_C) {
      const float u = uc[(size_t)ray * N_C + i];
      const float zs = __fadd_rn(__fmul_rn((float)i, lindelta), __fmul_rn(u, 0.001f));
      const float zc = __fadd_rn(__fmul_rn(nearv, __fsub_rn(1.0f, zs)), __fmul_rn(farv, zs));
      zg[cch] = zc;
      s_zc[i] = zc;
    }
  }

#pragma unroll 1
  for (int v = 0; v < N_V; ++v) {
    const float* pp = poses + (size_t)(sb * N_V + v) * 16;
    const float R00 = pp[0], R01 = pp[1], R02 = pp[2], t0 = pp[3];
    const float R10 = pp[4], R11 = pp[5], R12 = pp[6], t1 = pp[7];
    const float R20 = pp[8], R21 = pp[9], R22 = pp[10], t2 = pp[11];
    const float fx = focal[(sb * N_V + v) * 2 + 0];
    const float fy = focal[(sb * N_V + v) * 2 + 1];
    const float cx = cvec[(sb * N_V + v) * 2 + 0];
    const float cy = cvec[(sb * N_V + v) * 2 + 1];
    const float rdx = __fadd_rn(__fadd_rn(__fmul_rn(R00, dx), __fmul_rn(R01, dy)), __fmul_rn(R02, dz));
    const float rdy = __fadd_rn(__fadd_rn(__fmul_rn(R10, dx), __fmul_rn(R11, dy)), __fmul_rn(R12, dz));
    const float rdz = __fadd_rn(__fadd_rn(__fmul_rn(R20, dx), __fmul_rn(R21, dy)), __fmul_rn(R22, dz));
    const float* dmv = dmap + (size_t)(sb * N_V + v) * HW;
    const float* smv = smap + (size_t)(sb * N_V + v) * HW;
    const float* nmv = nmap + (size_t)(sb * N_V + v) * 3 * HW;

    // stage 1: project all 4 chunks, issue all 4 rd loads (pipelined).
    int   linv[4];
    float Zcv[4];
    float rdv[4];
#pragma unroll
    for (int cch = 0; cch < 4; ++cch) {
      const float zc = zg[cch];
      const float xw = __fadd_rn(ox, __fmul_rn(zc, dx));
      const float yw = __fadd_rn(oy, __fmul_rn(zc, dy));
      const float zw = __fadd_rn(oz, __fmul_rn(zc, dz));
      const float Xc = __fadd_rn(__fadd_rn(__fadd_rn(__fmul_rn(R00, xw), __fmul_rn(R01, yw)), __fmul_rn(R02, zw)), t0);
      const float Yc = __fadd_rn(__fadd_rn(__fadd_rn(__fmul_rn(R10, xw), __fmul_rn(R11, yw)), __fmul_rn(R12, zw)), t1);
      const float Zc = __fadd_rn(__fadd_rn(__fadd_rn(__fmul_rn(R20, xw), __fmul_rn(R21, yw)), __fmul_rn(R22, zw)), t2);
      const float iu = __fdiv_rn(Xc, Zc);
      const float iv = __fdiv_rn(Yc, Zc);
      const float su = __fadd_rn(__fmul_rn(iu, fx), cx);
      const float sv = __fadd_rn(__fmul_rn(iv, fy), cy);
      const float unorm = __fsub_rn(__fmul_rn(__fmul_rn(su, 1.0f / 256.0f), 2.0f), 1.0f);
      const float vnorm = __fsub_rn(__fmul_rn(__fmul_rn(sv, 1.0f / 256.0f), 2.0f), 1.0f);
      const float xf = __fsub_rn(__fmul_rn(__fmul_rn(__fadd_rn(unorm, 1.0f), 0.5f), 256.0f), 0.5f);
      const float yf = __fsub_rn(__fmul_rn(__fmul_rn(__fadd_rn(vnorm, 1.0f), 0.5f), 256.0f), 0.5f);
      const int px = (int)fminf(fmaxf(rintf(xf), 0.0f), 255.0f);
      const int py = (int)fminf(fmaxf(rintf(yf), 0.0f), 255.0f);
      linv[cch] = py * 256 + px;
      Zcv[cch] = Zc;
      rdv[cch] = dmv[linv[cch]];
    }

    // stage 2: depth-gate (~3% pass) -> remaining gathers + erf only then.
#pragma unroll
    for (int cch = 0; cch < 4; ++cch) {
      const int i = cch * 256 + tid;
      const float Zc = Zcv[cch];
      const float rd = rdv[cch];
      if (i < N_C && fabsf(__fsub_rn(rd, Zc)) < 0.05f) {
        const int lin = linv[cch];
        const float rs = smv[lin];
        const float n0 = nmv[lin];
        const float n1 = nmv[HW + lin];
        const float n2 = nmv[2 * HW + lin];
        const float cosd = __fadd_rn(__fadd_rn(__fmul_rn(rdx, n0), __fmul_rn(rdy, n1)), __fmul_rn(rdz, n2));
        if ((rs != 0.0f) && (cosd <= 0.0f)) {
          const float invv = __fdiv_rn(1.0f, __fmul_rn(rs, SQRT2));
          const float a1 = __fmul_rn(__fsub_rn(__fadd_rn(Zc, sshalf), rd), invv);
          const float a2 = __fmul_rn(__fsub_rn(__fsub_rn(Zc, sshalf), rd), invv);
          const float ptv = __fmul_rn(0.5f, fabsf(__fsub_rn(erf_xla(a1), erf_xla(a2))));
          ptg[cch] = fmaxf(ptg[cch], ptv);
        }
      }
    }
  }
#pragma unroll
  for (int cch = 0; cch < 4; ++cch) {
    const int i = cch * 256 + tid;
    if (i < N_C) s_pt[i] = ptg[cch];
  }
  __syncthreads();                                    // #1

  // ---------------- ownership switch: thread owns 4 consecutive samples ------
  const bool act = (tid < 250);
  float ptm[4] = {0.0f, 0.0f, 0.0f, 0.0f};
  float zcr[4] = {0.0f, 0.0f, 0.0f, 0.0f};
  if (act) {
    const float4 p4 = *(const float4*)&s_pt[tid * 4];
    ptm[0] = p4.x; ptm[1] = p4.y; ptm[2] = p4.z; ptm[3] = p4.w;
    const float4 z4 = *(const float4*)&s_zc[tid * 4];
    zcr[0] = z4.x; zcr[1] = z4.y; zcr[2] = z4.z; zcr[3] = z4.w;
  }

  // ---------------- Phase B: block scan + moments ----------------------------
  float lp = 1.0f;
  if (act) {
#pragma unroll
    for (int k = 0; k < 4; ++k) lp = __fmul_rn(lp, __fsub_rn(1.0f, ptm[k]));
  }
  float inc = lp;
#pragma unroll
  for (int off = 1; off < 64; off <<= 1) {
    float o = __shfl_up(inc, off);
    if (lane >= off) inc *= o;
  }
  if (lane == 63) s_wtot[wid] = inc;
  __syncthreads();                                    // #2
  float pw = 1.0f;
  if (wid > 0) pw *= s_wtot[0];
  if (wid > 1) pw *= s_wtot[1];
  if (wid > 2) pw *= s_wtot[2];
  float exc = __shfl_up(inc, 1);
  if (lane == 0) exc = 1.0f;
  exc *= pw;

  float accO = 0.0f, accZO = 0.0f;
  bool anynz = false;
  if (act) {
    float run = exc;
#pragma unroll
    for (int k = 0; k < 4; ++k) {
      float o = ptm[k] * run;
      accO += o;
      accZO += zcr[k] * o;
      anynz |= (o != 0.0f);
      run *= (1.0f - ptm[k]);
    }
  }
  accO = wave_sum(accO);
  accZO = wave_sum(accZO);
  const int anyw = __any(anynz) ? 1 : 0;
  if (lane == 0) { s_sO[wid] = accO; s_sZ[wid] = accZO; s_fl[wid] = anyw; }
  __syncthreads();                                    // #3
  const float tO = s_sO[0] + s_sO[1] + s_sO[2] + s_sO[3];
  const float tZ = s_sZ[0] + s_sZ[1] + s_sZ[2] + s_sZ[3];
  const bool raymask = (s_fl[0] | s_fl[1] | s_fl[2] | s_fl[3]) != 0;
  const float swd = (tO > 0.0f) ? tO : 1.0f;
  const float meanz = __fdiv_rn(tZ, swd);

  float accV = 0.0f;
  if (act) {
    float run = exc;
#pragma unroll
    for (int k = 0; k < 4; ++k) {
      float o = ptm[k] * run;
      float d = zcr[k] - meanz;
      accV += o * d * d;
      run *= (1.0f - ptm[k]);
    }
  }
  accV = wave_sum(accV);
  if (lane == 0) s_sV[wid] = accV;
  __syncthreads();                                    // #4
  const float tV = s_sV[0] + s_sV[1] + s_sV[2] + s_sV[3];
  const float stdz = sqrtf(__fdiv_rn(tV, swd));

  // ---------------- Phase C0: compact nonzero candidates into LDS list -------
  // Statically-unrolled running offset: NO runtime-indexed local arrays
  // (rule #20 — r5's version put lv[]/li[]/lz[] in scratch: 49 MB HBM writes).
  // List order is nondeterministic (atomicAdd) but selection compares
  // (val desc, idx asc) exactly, so the OUTPUT is deterministic.
  {
    const bool nz0 = act && (ptm[0] > 0.0f);
    const bool nz1 = act && (ptm[1] > 0.0f);
    const bool nz2 = act && (ptm[2] > 0.0f);
    const bool nz3 = act && (ptm[3] > 0.0f);
    const int nloc = (int)nz0 + (int)nz1 + (int)nz2 + (int)nz3;
    int base = 0;
    if (nloc > 0) base = atomicAdd(&s_cnt, nloc);
    if (base + nloc <= CAP) {
      int off = base;
      if (nz0) { s_lv[off] = ptm[0]; s_li[off] = tid * 4 + 0; s_lz[off] = zcr[0]; ++off; }
      if (nz1) { s_lv[off] = ptm[1]; s_li[off] = tid * 4 + 1; s_lz[off] = zcr[1]; ++off; }
      if (nz2) { s_lv[off] = ptm[2]; s_li[off] = tid * 4 + 2; s_lz[off] = zcr[2]; ++off; }
      if (nz3) { s_lv[off] = ptm[3]; s_li[off] = tid * 4 + 3; s_lz[off] = zcr[3]; ++off; }
    }
  }
  __syncthreads();                                    // #5
  const int cnt = s_cnt;   // block-uniform

  if (cnt <= CAP) {
    // -------------- Phase C-fast: wave-0 top-25 over compacted list ----------
    if (wid == 0) {
      float rv[4]; int ri[4]; float rz[4];
#pragma unroll
      for (int j = 0; j < 4; ++j) {
        const int p = lane + j * 64;
        if (p < cnt) { rv[j] = s_lv[p]; ri[j] = s_li[p]; rz[j] = s_lz[p]; }
        else         { rv[j] = -2.0f; ri[j] = 0x40000000; rz[j] = 0.0f; }
      }
#pragma unroll 1
      for (int kk = 0; kk < 25; ++kk) {
        float bv = -2.0f; int bi = 0x40000000;
#pragma unroll
        for (int j = 0; j < 4; ++j) {
          if (rv[j] > bv || (rv[j] == bv && ri[j] < bi)) { bv = rv[j]; bi = ri[j]; }
        }
#pragma unroll
        for (int off = 1; off < 64; off <<= 1) {
          const float ov = __shfl_xor(bv, off);
          const int oi = __shfl_xor(bi, off);
          if (ov > bv || (ov == bv && oi < bi)) { bv = ov; bi = oi; }
        }
        if (bv <= 0.0f) break;   // rest of zsel stay 0 (== reference)
#pragma unroll
        for (int j = 0; j < 4; ++j) {
          if (ri[j] == bi) {      // unique global idx: exactly one lane fires
            s_zsel[kk] = rz[j];   // same-wave LDS RAW: in-order
            rv[j] = -1.0f;
          }
        }
      }
    }
  } else {
    // -------------- Phase C-fallback (exact, any data): old C1 + C2 ----------
    const int cbase = wid * 25;
#pragma unroll 1
    for (int kk = 0; kk < 25; ++kk) {
      float bv = -2.0f;
      int bi = 0x40000000;
      if (act) {
#pragma unroll
        for (int k = 0; k < 4; ++k) {
          if (ptm[k] > bv) { bv = ptm[k]; bi = tid * 4 + k; }
        }
      }
#pragma unroll
      for (int off = 1; off < 64; off <<= 1) {
        float ov = __shfl_xor(bv, off);
        int oi = __shfl_xor(bi, off);
        if (ov > bv || (ov == bv && oi < bi)) { bv = ov; bi = oi; }
      }
      if (bv <= 0.0f) break;
      if (tid == (bi >> 2)) {
        s_cv[cbase + kk] = bv;
        s_ci[cbase + kk] = bi;
        const int r = bi & 3;
        float zk;
        if (r == 0)      { zk = zcr[0]; ptm[0] = -1.0f; }
        else if (r == 1) { zk = zcr[1]; ptm[1] = -1.0f; }
        else if (r == 2) { zk = zcr[2]; ptm[2] = -1.0f; }
        else             { zk = zcr[3]; ptm[3] = -1.0f; }
        s_cz[cbase + kk] = zk;
      }
    }
    __syncthreads();
    if (wid == 0) {
      float c0v = s_cv[lane];
      int   c0i = s_ci[lane];
      float c0z = s_cz[lane];
      float c1v = -2.0f; int c1i = 0x40000000; float c1z = 0.0f;
      if (lane + 64 < 100) { c1v = s_cv[lane + 64]; c1i = s_ci[lane + 64]; c1z = s_cz[lane + 64]; }
#pragma unroll 1
      for (int kk = 0; kk < 25; ++kk) {
        float bv = c0v; int bi = c0i; float bz = c0z;
        if (c1v > bv || (c1v == bv && c1i < bi)) { bv = c1v; bi = c1i; bz = c1z; }
#pragma unroll
        for (int off = 1; off < 64; off <<= 1) {
          float ov = __shfl_xor(bv, off);
          int oi = __shfl_xor(bi, off);
          float oz = __shfl_xor(bz, off);
          if (ov > bv || (ov == bv && oi < bi)) { bv = ov; bi = oi; bz = oz; }
        }
        if (bv <= 0.0f) break;
        if (lane == 0) s_zsel[kk] = bz;
        if (c0i == bi) c0v = -1.0f;
        if (c1i == bi) c1v = -1.0f;
      }
    }
  }

  // ---------------- Phase D/E: gaussian slots, sort, fill, sort (wave 0) -----
  if (wid == 0) {
    float sortv;
    if (lane < N_S - N_G) {
      sortv = s_zsel[lane];
    } else if (lane < N_S) {
      const float g = gn[(size_t)ray * N_G + (lane - (N_S - N_G))];
      sortv = raymask ? (g * stdz + meanz) : 0.0f;
    } else {
      sortv = INFINITY;
    }
    float z = bitonic64(sortv, lane);
    const bool miss = (lane < N_S) && (z == 0.0f);
    const int nmiss_raw = __popcll(__ballot(miss));
    const int nmiss = (nmiss_raw < 1) ? 1 : nmiss_raw;
    const float stepf = __fdiv_rn(__fsub_rn(farv, nearv), (float)nmiss);
    if (miss) {
      const float ufv = uf[(size_t)ray * N_S + lane];
      z = __fadd_rn(__fadd_rn(nearv, __fmul_rn((float)lane, stepf)), __fmul_rn(ufv, stepf));
    }
    z = bitonic64(z, lane);
    const float zn = __shfl_down(z, 1);
    const float delta = (lane == N_S - 1) ? (farv - z) : (zn - z);
    if (lane < N_S) { s_zarr[lane] = z; s_darr[lane] = delta; }
  }
  __syncthreads();                                    // #6

  // ---------------- Phase F1: MLP, 10 samples/wave, multi-channel reduce -----
  {
    const float b2r = (lane < 4) ? b2[lane] : 0.0f;
    float w1r[24], b1r[4], w2r[16];
#pragma unroll
    for (int m = 0; m < 4; ++m) {
      const int j = lane + 64 * m;
#pragma unroll
      for (int k = 0; k < 6; ++k) w1r[k * 4 + m] = W1[k * N_HID + j];
      b1r[m] = b1[j];
      const float4 w2v = *(const float4*)(W2 + (size_t)j * 4);
      w2r[m * 4 + 0] = w2v.x; w2r[m * 4 + 1] = w2v.y;
      w2r[m * 4 + 2] = w2v.z; w2r[m * 4 + 3] = w2v.w;
    }
#pragma unroll 1
    for (int q = 0; q < 10; ++q) {
      const int s = wid * 10 + q;
      const float zq = s_zarr[s];
      const float px = ox + zq * dx;
      const float py = oy + zq * dy;
      const float pz = oz + zq * dz;
      float a0 = 0.0f, a1 = 0.0f, a2 = 0.0f, a3 = 0.0f;
#pragma unroll
      for (int m = 0; m < 4; ++m) {
        float h = b1r[m];
        h = fmaf(px, w1r[0 * 4 + m], h);
        h = fmaf(py, w1r[1 * 4 + m], h);
        h = fmaf(pz, w1r[2 * 4 + m], h);
        h = fmaf(dx, w1r[3 * 4 + m], h);
        h = fmaf(dy, w1r[4 * 4 + m], h);
        h = fmaf(dz, w1r[5 * 4 + m], h);
        h = fmaxf(h, 0.0f);
        a0 = fmaf(h, w2r[m * 4 + 0], a0);
        a1 = fmaf(h, w2r[m * 4 + 1], a1);
        a2 = fmaf(h, w2r[m * 4 + 2], a2);
        a3 = fmaf(h, w2r[m * 4 + 3], a3);
      }
      // multi-channel butterfly: lane (l&3) ends with channel (l&3) total
      const float s0 = __shfl_xor(a0, 1), s1 = __shfl_xor(a1, 1);
      const float s2 = __shfl_xor(a2, 1), s3 = __shfl_xor(a3, 1);
      const float m0 = (lane & 1) ? (a1 + s1) : (a0 + s0);
      const float m1 = (lane & 1) ? (a3 + s3) : (a2 + s2);
      const float t0 = __shfl_xor(m0, 2), t1 = __shfl_xor(m1, 2);
      float r = (lane & 2) ? (m1 + t1) : (m0 + t0);
#pragma unroll
      for (int off = 4; off < 64; off <<= 1) r += __shfl_xor(r, off);
      if (lane < 4) s_mlp[s * 4 + lane] = r + b2r;
    }
  }
  __syncthreads();                                    // #7

  // ---------------- Phase F2: composite + output (wave 0) --------------------
  if (wid == 0) {
    float alpha = 0.0f, r0 = 0.0f, r1 = 0.0f, r2 = 0.0f, zl = 0.0f;
    float factor = 1.0f;
    if (lane < N_S) {
      zl = s_zarr[lane];
      const float dl = s_darr[lane];
      r0 = s_mlp[lane * 4 + 0];
      r1 = s_mlp[lane * 4 + 1];
      r2 = s_mlp[lane * 4 + 2];
      const float rsig = fmaxf(s_mlp[lane * 4 + 3], 0.0f);
      alpha = 1.0f - expf(-dl * rsig);
      factor = (1.0f - alpha) + 1e-10f;
    }
    float incp = factor;
#pragma unroll
    for (int off = 1; off < 64; off <<= 1) {
      float o = __shfl_up(incp, off);
      if (lane >= off) incp *= o;
    }
    float T = __shfl_up(incp, 1);
    if (lane == 0) T = 1.0f;

    const float w = (lane < N_S) ? alpha * T : 0.0f;
    const float wz = (lane < N_S) ? w * zl : 0.0f;
    const float wr0 = (lane < N_S) ? w * r0 : 0.0f;
    const float wr1 = (lane < N_S) ? w * r1 : 0.0f;
    const float wr2 = (lane < N_S) ? w * r2 : 0.0f;

    const float wsum = wave_sum(w);
    const float dsum = wave_sum(wz);
    const float c0s = wave_sum(wr0);
    const float c1s = wave_sum(wr1);
    const float c2s = wave_sum(wr2);

    if (lane < N_S) out[(size_t)ray * N_S + lane] = w;
    if (lane == 0) {
      float* rgbo = out + (size_t)N_SB * N_R * N_S + (size_t)ray * 3;
      rgbo[0] = (c0s + 1.0f) - wsum;
      rgbo[1] = (c1s + 1.0f) - wsum;
      rgbo[2] = (c2s + 1.0f) - wsum;
      out[(size_t)N_SB * N_R * N_S + (size_t)N_SB * N_R * 3 + ray] = dsum;
    }
  }
}

extern "C" void kernel_launch(void* const* d_in, const int* in_sizes, int n_in,
                              void* d_out, int out_size, void* d_ws, size_t ws_size,
                              hipStream_t stream) {
  const float* rays  = (const float*)d_in[0];
  const float* poses = (const float*)d_in[1];
  const float* focal = (const float*)d_in[2];
  const float* cvec  = (const float*)d_in[3];
  const float* dmap  = (const float*)d_in[4];
  const float* smap  = (const float*)d_in[5];
  const float* nmap  = (const float*)d_in[6];
  const float* W1p   = (const float*)d_in[7];
  const float* b1p   = (const float*)d_in[8];
  const float* W2p   = (const float*)d_in[9];
  const float* b2p   = (const float*)d_in[10];
  const float* ucp   = (const float*)d_in[11];
  const float* gnp   = (const float*)d_in[12];
  const float* ufp   = (const float*)d_in[13];
  float* outp = (float*)d_out;

  dim3 grid(N_SB * N_R);   // one ray per block
  dim3 block(256);
  nerf_all<<<grid, block, 0, stream>>>(rays, poses, focal, cvec, dmap, smap, nmap,
                                       W1p, b1p, W2p, b2p, ucp, gnp, ufp, outp);
}